// Round 10
// baseline (1405.974 us; speedup 1.0000x reference)
//
#include <hip/hip_runtime.h>
#include <cstdint>
#include <cstddef>

// Problem constants (fixed by setup_inputs)
#define BB    16
#define NTOK  4096
#define DIMC  512
#define INNER 512
#define CTXC  256
#define HEADS 8
#define HD    64
#define AG    49
#define ASPLIT 8   // n-splits for agent attention
#define CONVK 6912
#define CKS   16   // k-splits for conv GEMM (chunk = 432 = 27*16)

// ---------------- workspace layout (floats) ----------------
static const size_t Q_OFF   = 0;                                     // q / out_pre: 16*4096*512
static const size_t KV_OFF  = Q_OFF  + (size_t)BB*NTOK*INNER;        // k_buf: 16*4096*512, then v_buf: 16*4096*512
static const size_t A2_OFF  = KV_OFF + (size_t)BB*NTOK*2*INNER;      // pooled concat: 16*49*768
static const size_t COL_OFF = A2_OFF + (size_t)BB*AG*768;            // im2col: 784*6912 (pool S1q scratch before; attn partials + avT after)
static const size_t CG_OFF  = COL_OFF+ (size_t)BB*AG*768*9;          // conv gemm out: 784*512 (pool S1c scratch)
static const size_t AGT_OFF = CG_OFF + (size_t)BB*AG*INNER;          // agent[b,h,a,d]
static const size_t AGV_OFF = AGT_OFF+ (size_t)BB*HEADS*AG*HD;       // (retired)
static const size_t PB_OFF  = AGV_OFF+ (size_t)BB*HEADS*AG*HD;       // pb[h,a,n]
static const size_t AB_OFF  = PB_OFF + (size_t)HEADS*AG*NTOK;        // ab[h,n,a]
static const size_t WSP_OFF = AB_OFF + (size_t)HEADS*NTOK*AG;        // pre-split weights: 2*2048*512 shorts = 1,048,576 floats
// overlays of the retired COL region:
static const size_t PNUM_OFF = COL_OFF;                              // 8*128*64*64 = 4,194,304 floats
static const size_t PL_OFF   = PNUM_OFF + (size_t)ASPLIT*128*64*64;  // 8*128*64    = 65,536 floats
static const size_t AVT_OFF  = PL_OFF + (size_t)ASPLIT*128*64;       // avT hi/lo: 2*128*64*64 shorts = 524,288 floats
// (4,259,840 + 524,288 = 4,784,128 < COL region's 5,419,008 floats)

typedef __attribute__((ext_vector_type(8))) short  short8;   // 8 bf16 bit-patterns (4 VGPRs)
typedef __attribute__((ext_vector_type(8))) __bf16 bf16x8;   // canonical MFMA operand type
typedef __attribute__((ext_vector_type(4))) float  f32x4;    // MFMA accumulator

union SB8 { short8 s; bf16x8 b; };

__device__ inline bf16x8 asbf(short8 v) { SB8 u; u.s = v; return u.b; }

// round-to-nearest-even fp32 -> bf16 bits
__device__ inline unsigned short bfrn(float x) {
  uint32_t u = __float_as_uint(x);
  return (unsigned short)((u + 0x7FFFu + ((u >> 16) & 1u)) >> 16);
}

struct HL8 { short8 h, l; };

// split 8 fp32 into bf16 hi (RNE) + bf16 lo (RNE) — used once for weights
__device__ inline HL8 split8(float4 f0, float4 f1) {
  HL8 r;
  float v0[4] = {f0.x, f0.y, f0.z, f0.w};
  float v1[4] = {f1.x, f1.y, f1.z, f1.w};
#pragma unroll
  for (int j = 0; j < 4; ++j) {
    unsigned short hb = bfrn(v0[j]);
    r.h[j] = (short)hb;
    r.l[j] = (short)bfrn(v0[j] - __uint_as_float((uint32_t)hb << 16));
  }
#pragma unroll
  for (int j = 0; j < 4; ++j) {
    unsigned short hb = bfrn(v1[j]);
    r.h[j + 4] = (short)hb;
    r.l[j + 4] = (short)bfrn(v1[j] - __uint_as_float((uint32_t)hb << 16));
  }
  return r;
}

// TRUNC-TRUNC split: hi=trunc(v), lo=trunc(v-hi). v-hi is EXACT (same exponent),
// so hi+lo reconstruction error <= 2^-16|v| — same as RNE-hi, at ~half the VALU ops.
__device__ inline HL8 split8t(float4 f0, float4 f1) {
  HL8 r;
  float v[8] = {f0.x, f0.y, f0.z, f0.w, f1.x, f1.y, f1.z, f1.w};
#pragma unroll
  for (int j = 0; j < 8; ++j) {
    uint32_t u = __float_as_uint(v[j]);
    r.h[j] = (short)(u >> 16);
    float res = v[j] - __uint_as_float(u & 0xFFFF0000u);
    r.l[j] = (short)(__float_as_uint(res) >> 16);
  }
  return r;
}

// ---------------- one-time weight split: fp32 -> bf16 hi/lo ----------------
__global__ void split_w_kernel(const float* __restrict__ src, short* __restrict__ dhi,
                               short* __restrict__ dlo, int n8) {
  int i = blockIdx.x * 256 + threadIdx.x;
  if (i >= n8) return;
  const float4* s = (const float4*)src + (size_t)i * 2;
  HL8 r = split8(s[0], s[1]);
  *(short8*)(dhi + (size_t)i * 8) = r.h;
  *(short8*)(dlo + (size_t)i * 8) = r.l;
}

// ---------------- MFMA split-bf16 GEMM, 128x128 tile: [C1|C2|C3] = A(MxK) * Bw^T (+bias) ----------------
// 3-pass hi/lo split: C = Ah*Bh + Ah*Bl + Al*Bh. B pre-split bf16.
// XCD-aware block swizzle (nwg % 8 == 0). Output col-tile t = bnT>>9 routes to C1/C2/C3 (each 512 wide).
// LDS row stride 40 (R6 config — measured 381us; XOR-swizzle variant REGRESSED, reverted)
#define LSTR 40
template <bool ADD_BIAS>
__global__ __launch_bounds__(256) void gemm_ws3(const float* __restrict__ A,
                                                const short* __restrict__ Bhi_g,
                                                const short* __restrict__ Blo_g,
                                                const float* __restrict__ bias,
                                                float* __restrict__ C1,
                                                float* __restrict__ C2,
                                                float* __restrict__ C3,
                                                int M, int K) {
  __shared__ short Ahi[128 * LSTR];
  __shared__ short Alo[128 * LSTR];
  __shared__ short Bhi[128 * LSTR];
  __shared__ short Blo[128 * LSTR];
  const int tid  = threadIdx.x;
  const int lane = tid & 63;
  const int wave = tid >> 6;
  const int wm = wave >> 1, wn = wave & 1;          // 2x2 wave grid
  // XCD-aware swizzle: consecutive blocks within an XCD share an A m-panel
  const int nwg = gridDim.x * gridDim.y;
  const int lin = blockIdx.y * gridDim.x + blockIdx.x;
  const int swz = (lin & 7) * (nwg >> 3) + (lin >> 3);
  const int bx = swz % gridDim.x, by = swz / gridDim.x;
  const int bm = by * 128, bnT = bx * 128;
  // staging role: 2 threads per row, 16 consecutive k each
  const int srow  = tid >> 1;
  const int shalf = (tid & 1) << 4;                 // 0 or 16 (elements)
  // fragment role
  const int fr  = lane & 15;                        // row/col within 16x16 frag
  const int fko = (lane >> 4) << 3;                 // k offset: 0,8,16,24

  f32x4 acc[4][4] = {};

  for (int k0 = 0; k0 < K; k0 += 32) {
    {
      // A: fp32 load + in-kernel trunc-trunc split
      const float4* ap = (const float4*)(A + (size_t)(bm + srow) * K + k0 + shalf);
      float4 a0 = ap[0], a1 = ap[1], a2 = ap[2], a3 = ap[3];
      HL8 r0 = split8t(a0, a1);
      *(short8*)&Ahi[srow * LSTR + shalf] = r0.h;
      *(short8*)&Alo[srow * LSTR + shalf] = r0.l;
      HL8 r1 = split8t(a2, a3);
      *(short8*)&Ahi[srow * LSTR + shalf + 8] = r1.h;
      *(short8*)&Alo[srow * LSTR + shalf + 8] = r1.l;
      // B: pre-split bf16, straight copy to LDS
      const short* bhp = Bhi_g + (size_t)(bnT + srow) * K + k0 + shalf;
      *(short8*)&Bhi[srow * LSTR + shalf]     = *(const short8*)bhp;
      *(short8*)&Bhi[srow * LSTR + shalf + 8] = *(const short8*)(bhp + 8);
      const short* blp = Blo_g + (size_t)(bnT + srow) * K + k0 + shalf;
      *(short8*)&Blo[srow * LSTR + shalf]     = *(const short8*)blp;
      *(short8*)&Blo[srow * LSTR + shalf + 8] = *(const short8*)(blp + 8);
    }
    __syncthreads();
    bf16x8 ah[4], al[4], bh[4], bl[4];
#pragma unroll
    for (int i = 0; i < 4; ++i) {
      int ra = wm * 64 + i * 16 + fr;
      ah[i] = asbf(*(const short8*)&Ahi[ra * LSTR + fko]);
      al[i] = asbf(*(const short8*)&Alo[ra * LSTR + fko]);
      int rb = wn * 64 + i * 16 + fr;
      bh[i] = asbf(*(const short8*)&Bhi[rb * LSTR + fko]);
      bl[i] = asbf(*(const short8*)&Blo[rb * LSTR + fko]);
    }
#pragma unroll
    for (int i = 0; i < 4; ++i)
#pragma unroll
      for (int j = 0; j < 4; ++j) {
        acc[i][j] = __builtin_amdgcn_mfma_f32_16x16x32_bf16(ah[i], bh[j], acc[i][j], 0, 0, 0);
        acc[i][j] = __builtin_amdgcn_mfma_f32_16x16x32_bf16(ah[i], bl[j], acc[i][j], 0, 0, 0);
        acc[i][j] = __builtin_amdgcn_mfma_f32_16x16x32_bf16(al[i], bh[j], acc[i][j], 0, 0, 0);
      }
    __syncthreads();
  }

  // epilogue: C/D layout col=lane&15, row=4*(lane>>4)+reg; route to C1/C2/C3 (512 cols each)
  const int crow0 = wm * 64 + ((lane >> 4) << 2);
  const int ccol0 = wn * 64 + fr;
  const int t = bnT >> 9;
  float* Cb = (t == 0) ? C1 : (t == 1) ? C2 : C3;
  const int coff = bnT & 511;
  float bs[4];
  if (ADD_BIAS) {
#pragma unroll
    for (int j = 0; j < 4; ++j) bs[j] = bias[bnT + ccol0 + j * 16];
  }
#pragma unroll
  for (int i = 0; i < 4; ++i) {
#pragma unroll
    for (int r = 0; r < 4; ++r) {
      size_t row = (size_t)(bm + crow0 + i * 16 + r);
      float* cp = Cb + row * 512 + coff + ccol0;
#pragma unroll
      for (int j = 0; j < 4; ++j) {
        float v = acc[i][j][r];
        if (ADD_BIAS) v += bs[j];
        cp[j * 16] = v;
      }
    }
  }
}

// ---------------- zero-fill (graph-capture-safe memset) ----------------
__global__ void zero_kernel(float* __restrict__ p, int n) {
  int i = blockIdx.x * 256 + threadIdx.x;
  if (i < n) p[i] = 0.f;
}

// ---------------- conv GEMM, split-K + atomics: Cg[784][512] += Col[784][6912] @ W[512][6912]^T ----------------
__global__ __launch_bounds__(256) void conv_gemm_splitk(const float* __restrict__ A,
                                                        const float* __restrict__ Bw,
                                                        float* __restrict__ C) {
  __shared__ float As[16][72];
  __shared__ float Bs[16][72];
  const int tid = threadIdx.x;
  const int tx = tid & 15, ty = tid >> 4;
  const int bn = blockIdx.x * 64;
  const int bm = blockIdx.y * 64;
  const int k_begin = blockIdx.z * (CONVK / CKS);
  const int k_end = k_begin + (CONVK / CKS);
  const int row = tid >> 2, c4 = (tid & 3) << 2;
  float acc[4][4] = {};
  for (int k0 = k_begin; k0 < k_end; k0 += 16) {
    {
      int m = bm + row;
      float4 av = {0.f, 0.f, 0.f, 0.f};
      if (m < 784) av = *(const float4*)(A + (size_t)m * CONVK + k0 + c4);
      As[c4 + 0][row] = av.x; As[c4 + 1][row] = av.y;
      As[c4 + 2][row] = av.z; As[c4 + 3][row] = av.w;
      float4 bv = *(const float4*)(Bw + (size_t)(bn + row) * CONVK + k0 + c4);
      Bs[c4 + 0][row] = bv.x; Bs[c4 + 1][row] = bv.y;
      Bs[c4 + 2][row] = bv.z; Bs[c4 + 3][row] = bv.w;
    }
    __syncthreads();
#pragma unroll
    for (int k = 0; k < 16; ++k) {
      float a[4], b[4];
#pragma unroll
      for (int i = 0; i < 4; ++i) a[i] = As[k][ty * 4 + i];
#pragma unroll
      for (int j = 0; j < 4; ++j) b[j] = Bs[k][tx * 4 + j];
#pragma unroll
      for (int i = 0; i < 4; ++i)
#pragma unroll
        for (int j = 0; j < 4; ++j) acc[i][j] = fmaf(a[i], b[j], acc[i][j]);
    }
    __syncthreads();
  }
#pragma unroll
  for (int i = 0; i < 4; ++i) {
    int m = bm + ty * 4 + i;
    if (m >= 784) continue;
#pragma unroll
    for (int j = 0; j < 4; ++j)
      atomicAdd(C + (size_t)m * INNER + bn + tx * 4 + j, acc[i][j]);
  }
}

// ---------------- separable overlapping avg-pool, stage 1: pool over h ----------------
__global__ void pool_h_kernel(const float* __restrict__ q, const float* __restrict__ ctx,
                              float* __restrict__ S1q, float* __restrict__ S1c) {
  int idx = blockIdx.x * 256 + threadIdx.x;    // 16*7*64*768
  if (idx >= BB * 7 * 64 * 768) return;
  int c  = idx % 768;
  int w  = (idx / 768) & 63;
  int ph = (idx / (768 * 64)) % 7;
  int b  = idx / (768 * 64 * 7);
  int hs = ph * 64 / 7, he = ((ph + 1) * 64 + 6) / 7;
  float s = 0.f;
  if (c < 512) {
    const float* p = q + ((size_t)b * NTOK + hs * 64 + w) * INNER + c;
    for (int h = hs; h < he; ++h) { s += *p; p += 64 * INNER; }
    S1q[((size_t)(b * 7 + ph) * 64 + w) * 512 + c] = s;
  } else {
    int cc = c - 512;
    const float* p = ctx + ((size_t)b * NTOK + hs * 64 + w) * CTXC + cc;
    for (int h = hs; h < he; ++h) { s += *p; p += 64 * CTXC; }
    S1c[((size_t)(b * 7 + ph) * 64 + w) * 256 + cc] = s;
  }
}

// ---------------- pool stage 2: pool over w, normalize -> A2[b,49,768] ----------------
__global__ void pool_w_kernel(const float* __restrict__ S1q, const float* __restrict__ S1c,
                              float* __restrict__ A2) {
  int idx = blockIdx.x * 256 + threadIdx.x;    // 16*49*768
  if (idx >= BB * AG * 768) return;
  int c = idx % 768;
  int p = (idx / 768) % AG;
  int b = idx / (768 * AG);
  int i = p / 7, j = p % 7;
  int hs = i * 64 / 7, he = ((i + 1) * 64 + 6) / 7;
  int ws = j * 64 / 7, we = ((j + 1) * 64 + 6) / 7;
  float inv = 1.f / (float)((he - hs) * (we - ws));
  float s = 0.f;
  if (c < 512) {
    const float* pp = S1q + ((size_t)(b * 7 + i) * 64 + ws) * 512 + c;
    for (int w = ws; w < we; ++w) { s += *pp; pp += 512; }
  } else {
    const float* pp = S1c + ((size_t)(b * 7 + i) * 64 + ws) * 256 + (c - 512);
    for (int w = ws; w < we; ++w) { s += *pp; pp += 256; }
  }
  A2[((size_t)b * AG + p) * 768 + c] = s * inv;
}

// ---------------- im2col of scrambled agent_in: Col[b*49+p][ic*9+ky*3+kx] ----------------
__global__ void im2col_kernel(const float* __restrict__ A2, float* __restrict__ Col) {
  int idx = blockIdx.x * 256 + threadIdx.x;    // 784*6912
  if (idx >= 784 * 6912) return;
  int r = idx / 6912, t = idx % 6912;
  int ic = t / 9, ky = (t % 9) / 3, kx = t % 3;
  int b = r / AG, p = r % AG;
  int y = p / 7 + ky - 1, x = p % 7 + kx - 1;
  float v = 0.f;
  if (y >= 0 && y < 7 && x >= 0 && x < 7) {
    int g = ic * 49 + y * 7 + x;
    v = A2[((size_t)b * AG + g / 768) * 768 + (g % 768)];
  }
  Col[(size_t)idx] = v;
}

// ---------------- scramble conv output -> agent[b,h,a,d] (+conv bias) ----------------
__global__ void agent_scatter_kernel(const float* __restrict__ Cg, const float* __restrict__ conv_b,
                                     float* __restrict__ agent) {
  int idx = blockIdx.x * 256 + threadIdx.x;   // 16*8*49*64
  if (idx >= BB * HEADS * AG * HD) return;
  int d = idx & 63;
  int a = (idx >> 6) % AG;
  int h = (idx / (64 * AG)) % HEADS;
  int b = idx / (64 * AG * HEADS);
  int f = a * 512 + h * 64 + d;
  int oc = f / 49, p = f % 49;
  agent[idx] = Cg[((size_t)b * AG + p) * INNER + oc] + conv_b[oc];
}

// ---------------- jax bilinear resize 7->64 (half-pixel, renorm == clamp) ----------------
__device__ inline float bilinear7(const float* __restrict__ Bm, int y, int x) {
  float fy = (y + 0.5f) * (7.f / 64.f) - 0.5f;
  float fx = (x + 0.5f) * (7.f / 64.f) - 0.5f;
  fy = fminf(fmaxf(fy, 0.f), 6.f);
  fx = fminf(fmaxf(fx, 0.f), 6.f);
  int y0 = min((int)floorf(fy), 5);
  int x0 = min((int)floorf(fx), 5);
  float ty = fy - y0, tx = fx - x0;
  float v00 = Bm[y0 * 7 + x0],     v01 = Bm[y0 * 7 + x0 + 1];
  float v10 = Bm[(y0 + 1) * 7 + x0], v11 = Bm[(y0 + 1) * 7 + x0 + 1];
  return (1.f - ty) * ((1.f - tx) * v00 + tx * v01) + ty * ((1.f - tx) * v10 + tx * v11);
}

// pb[h][a][n] = resize(an_bias[h,a])(y,x) + ah[h,a,y] + aw[h,a,x]
__global__ void pb_kernel(const float* __restrict__ an_bias, const float* __restrict__ ah,
                          const float* __restrict__ aw, float* __restrict__ pb) {
  int idx = blockIdx.x * 256 + threadIdx.x;   // 8*49*4096
  if (idx >= HEADS * AG * NTOK) return;
  int nn = idx & (NTOK - 1);
  int a = (idx / NTOK) % AG;
  int h = idx / (NTOK * AG);
  int y = nn >> 6, x = nn & 63;
  float v = bilinear7(an_bias + ((size_t)h * AG + a) * 49, y, x);
  v += ah[((size_t)h * AG + a) * 64 + y] + aw[((size_t)h * AG + a) * 64 + x];
  pb[idx] = v;
}

// ab[h][n][a] = resize(na_bias[h,a])(y,x) + ha[h,y,a] + wa[h,x,a]
__global__ void ab_kernel(const float* __restrict__ na_bias, const float* __restrict__ ha,
                          const float* __restrict__ wa, float* __restrict__ ab) {
  int idx = blockIdx.x * 256 + threadIdx.x;   // 8*4096*49
  if (idx >= HEADS * NTOK * AG) return;
  int a = idx % AG;
  int nn = (idx / AG) & (NTOK - 1);
  int h = idx / (AG * NTOK);
  int y = nn >> 6, x = nn & 63;
  float v = bilinear7(na_bias + ((size_t)h * AG + a) * 49, y, x);
  v += ha[((size_t)h * 64 + y) * AG + a] + wa[((size_t)h * 64 + x) * AG + a];
  ab[idx] = v;
}

// ---------------- agent attention via MFMA (split-bf16 3-pass QK^T and PV) ----------------
// k_buf/v_buf are de-interleaved (512-float rows).
#define ESTR 72
__global__ __launch_bounds__(256, 2) void agent_attn_mfma(const float* __restrict__ k_g,
                                                          const float* __restrict__ v_g,
                                                          const float* __restrict__ agent,
                                                          const float* __restrict__ pb,
                                                          float* __restrict__ part_num,
                                                          float* __restrict__ part_l) {
  const int split = blockIdx.x;                 // 0..ASPLIT-1
  const int h = blockIdx.y, b = blockIdx.z;
  const int bh = b * HEADS + h;
  __shared__ short eThi[64 * ESTR];
  __shared__ short eTlo[64 * ESTR];
  __shared__ short vThi[64 * ESTR];
  __shared__ short vTlo[64 * ESTR];
  __shared__ float lred[4][64];
  const int tid = threadIdx.x;
  const int lane = tid & 63;
  const int w = tid >> 6;                       // wave id
  const int fr = lane & 15;
  const int fko = (lane >> 4) << 3;             // 0,8,16,24
  const int rg = lane >> 4;                     // C-layout row group

  // ---- persistent A-frags: agent rows a=i*16+fr (clamped; masked later), scaled 0.125, split ----
  bf16x8 agh[4][2], agl[4][2];
#pragma unroll
  for (int i = 0; i < 4; ++i) {
    int ar = i * 16 + fr; if (ar > AG - 1) ar = AG - 1;
#pragma unroll
    for (int kh = 0; kh < 2; ++kh) {
      const float4* p = (const float4*)(agent + ((size_t)bh * AG + ar) * HD + kh * 32 + fko);
      float4 f0 = p[0], f1 = p[1];
      f0.x *= 0.125f; f0.y *= 0.125f; f0.z *= 0.125f; f0.w *= 0.125f;
      f1.x *= 0.125f; f1.y *= 0.125f; f1.z *= 0.125f; f1.w *= 0.125f;
      HL8 r = split8t(f0, f1);
      agh[i][kh] = asbf(r.h); agl[i][kh] = asbf(r.l);
    }
  }

  float lacc[4][4] = {};       // [i][reg] per-lane l partials (this lane's n column)
  f32x4 oa[4] = {};            // PV acc: rows a=i*16+4rg+reg, col d=w*16+fr

  const float* kb = k_g + (size_t)b * NTOK * 512 + h * 64;   // k rows, stride 512
  const float* vb = v_g + (size_t)b * NTOK * 512 + h * 64;   // v rows, stride 512
  const float* pbh = pb + (size_t)h * AG * NTOK;
  const int nrow = tid & 63, dq = tid >> 6;                   // vT staging mapping

  for (int c = 0; c < 8; ++c) {
    const int n0 = split * 512 + c * 64;
    // ---- stage vT[d][n] split-bf16 ----
    {
      const float* vr = vb + (size_t)(n0 + nrow) * 512;
#pragma unroll
      for (int p = 0; p < 2; ++p) {
        int d0 = dq * 16 + p * 8;
        float4 f0 = *(const float4*)(vr + d0);
        float4 f1 = *(const float4*)(vr + d0 + 4);
        HL8 r = split8t(f0, f1);
#pragma unroll
        for (int j = 0; j < 8; ++j) {
          vThi[(d0 + j) * ESTR + nrow] = r.h[j];
          vTlo[(d0 + j) * ESTR + nrow] = r.l[j];
        }
      }
    }
    // ---- QK: B-frags from k row n = n0 + w*16 + fr ----
    bf16x8 kh_[2], kl_[2];
    {
      const float* kr = kb + (size_t)(n0 + w * 16 + fr) * 512;
#pragma unroll
      for (int kh = 0; kh < 2; ++kh) {
        float4 f0 = *(const float4*)(kr + kh * 32 + fko);
        float4 f1 = *(const float4*)(kr + kh * 32 + fko + 4);
        HL8 r = split8t(f0, f1);
        kh_[kh] = asbf(r.h); kl_[kh] = asbf(r.l);
      }
    }
    f32x4 sa[4] = {};
#pragma unroll
    for (int i = 0; i < 4; ++i)
#pragma unroll
      for (int kh = 0; kh < 2; ++kh) {
        sa[i] = __builtin_amdgcn_mfma_f32_16x16x32_bf16(agh[i][kh], kh_[kh], sa[i], 0, 0, 0);
        sa[i] = __builtin_amdgcn_mfma_f32_16x16x32_bf16(agh[i][kh], kl_[kh], sa[i], 0, 0, 0);
        sa[i] = __builtin_amdgcn_mfma_f32_16x16x32_bf16(agl[i][kh], kh_[kh], sa[i], 0, 0, 0);
      }
    // ---- e = exp(s + pb) masked; accumulate l; write trunc-split e to eT ----
    const int ncol = n0 + w * 16 + fr;
#pragma unroll
    for (int i = 0; i < 4; ++i)
#pragma unroll
      for (int r = 0; r < 4; ++r) {
        int a = i * 16 + 4 * rg + r;
        float e = 0.f;
        if (a < AG) e = __expf(sa[i][r] + pbh[(size_t)a * NTOK + ncol]);
        lacc[i][r] += e;
        uint32_t u = __float_as_uint(e);
        float res = e - __uint_as_float(u & 0xFFFF0000u);
        eThi[a * ESTR + w * 16 + fr] = (short)(u >> 16);
        eTlo[a * ESTR + w * 16 + fr] = (short)(__float_as_uint(res) >> 16);
      }
    __syncthreads();
    // ---- PV: A = eT rows, B = vT rows d = w*16+fr ----
    bf16x8 vh_[2], vl_[2];
#pragma unroll
    for (int kh = 0; kh < 2; ++kh) {
      vh_[kh] = asbf(*(const short8*)&vThi[(w * 16 + fr) * ESTR + kh * 32 + fko]);
      vl_[kh] = asbf(*(const short8*)&vTlo[(w * 16 + fr) * ESTR + kh * 32 + fko]);
    }
#pragma unroll
    for (int i = 0; i < 4; ++i)
#pragma unroll
      for (int kh = 0; kh < 2; ++kh) {
        bf16x8 eh = asbf(*(const short8*)&eThi[(i * 16 + fr) * ESTR + kh * 32 + fko]);
        bf16x8 el = asbf(*(const short8*)&eTlo[(i * 16 + fr) * ESTR + kh * 32 + fko]);
        oa[i] = __builtin_amdgcn_mfma_f32_16x16x32_bf16(eh, vh_[kh], oa[i], 0, 0, 0);
        oa[i] = __builtin_amdgcn_mfma_f32_16x16x32_bf16(eh, vl_[kh], oa[i], 0, 0, 0);
        oa[i] = __builtin_amdgcn_mfma_f32_16x16x32_bf16(el, vh_[kh], oa[i], 0, 0, 0);
      }
    __syncthreads();
  }

  // ---- l: reduce over fr (16-lane groups), then across waves via LDS ----
#pragma unroll
  for (int i = 0; i < 4; ++i)
#pragma unroll
    for (int r = 0; r < 4; ++r) {
      float l = lacc[i][r];
      l += __shfl_xor(l, 1, 64); l += __shfl_xor(l, 2, 64);
      l += __shfl_xor(l, 4, 64); l += __shfl_xor(l, 8, 64);
      lacc[i][r] = l;
    }
  if (fr == 0) {
#pragma unroll
    for (int i = 0; i < 4; ++i)
#pragma unroll
      for (int r = 0; r < 4; ++r)
        lred[w][i * 16 + 4 * rg + r] = lacc[i][r];
  }
  __syncthreads();

  float* pn = part_num + ((size_t)(split * 128 + bh)) * 64 * 64;
  float* pl = part_l + (size_t)(split * 128 + bh) * 64;
#pragma unroll
  for (int i = 0; i < 4; ++i)
#pragma unroll
    for (int r = 0; r < 4; ++r) {
      int a = i * 16 + 4 * rg + r;
      if (a < AG) pn[a * 64 + w * 16 + fr] = oa[i][r];
    }
  if (tid < AG) pl[tid] = lred[0][tid] + lred[1][tid] + lred[2][tid] + lred[3][tid];
}

// ---------------- combine partials -> transposed, split agent_v: avT[bh][d][a] bf16 hi/lo ----------------
__global__ void agent_attn_combine(const float* __restrict__ part_num,
                                   const float* __restrict__ part_l,
                                   short* __restrict__ avThi, short* __restrict__ avTlo) {
  int idx = blockIdx.x * 256 + threadIdx.x;   // 128*64*64
  if (idx >= 128 * 64 * 64) return;
  int a = idx & 63;
  int d = (idx >> 6) & 63;
  int bh = idx >> 12;
  float v = 0.f;
  if (a < AG) {
    float num = 0.f, l = 0.f;
#pragma unroll
    for (int s = 0; s < ASPLIT; ++s) {
      num += part_num[((size_t)(s * 128 + bh)) * 4096 + a * 64 + d];
      l += part_l[(size_t)(s * 128 + bh) * 64 + a];
    }
    v = num / l;
  }
  unsigned short hb = bfrn(v);
  float res = v - __uint_as_float((uint32_t)hb << 16);
  avThi[(size_t)bh * 4096 + d * 64 + a] = (short)hb;
  avTlo[(size_t)bh * 4096 + d * 64 + a] = (short)(__float_as_uint(res) >> 16);
}

// ---------------- q attention via MFMA: softmax_a(q*scale . agent^T + ab) @ agent_v ----------------
#define PSTR 80
__global__ __launch_bounds__(256) void q_attn_mfma(const float* __restrict__ agent,
                                                   const short* __restrict__ avThi,
                                                   const short* __restrict__ avTlo,
                                                   const float* __restrict__ ab,
                                                   float* __restrict__ q) {
  const int tile = blockIdx.x;   // 32 tiles of 128 tokens
  const int h = blockIdx.y, b = blockIdx.z;
  const int bh = b * HEADS + h;
  __shared__ short Phi[128 * PSTR];
  __shared__ short Plo[128 * PSTR];
  const int tid = threadIdx.x;
  const int lane = tid & 63;
  const int wave = tid >> 6;
  const int woff = wave * 32;          // token offset within tile
  const int fr = lane & 15;
  const int fko = (lane >> 4) << 3;    // 0,8,16,24
  const int rg = lane >> 4;            // C-layout row group

  const size_t agbase = (size_t)bh * AG * HD;
  const int gtok0 = tile * 128 + woff;              // token within [0,4096)
  const size_t qrow0 = (size_t)b * NTOK + gtok0;    // global q row of wave

  // ---- B-frags from agent rows (a = j*16+fr clamped), scaled 0.125, split in-register ----
  bf16x8 agh[2][4], agl[2][4];   // [khalf][j]
#pragma unroll
  for (int j = 0; j < 4; ++j) {
    int ar = j * 16 + fr; if (ar > AG - 1) ar = AG - 1;
#pragma unroll
    for (int kh = 0; kh < 2; ++kh) {
      const float4* p = (const float4*)(agent + agbase + (size_t)ar * HD + kh * 32 + fko);
      float4 f0 = p[0], f1 = p[1];
      f0.x *= 0.125f; f0.y *= 0.125f; f0.z *= 0.125f; f0.w *= 0.125f;
      f1.x *= 0.125f; f1.y *= 0.125f; f1.z *= 0.125f; f1.w *= 0.125f;
      HL8 r = split8t(f0, f1);
      agh[kh][j] = asbf(r.h); agl[kh][j] = asbf(r.l);
    }
  }

  // ---- A-frags from q rows (token = i*16+fr), split in-register ----
  bf16x8 qh_[2][2], ql_[2][2];   // [i][khalf]
#pragma unroll
  for (int i = 0; i < 2; ++i)
#pragma unroll
    for (int kh = 0; kh < 2; ++kh) {
      const float4* p = (const float4*)(q + (qrow0 + i * 16 + fr) * INNER + h * 64 + kh * 32 + fko);
      HL8 r = split8t(p[0], p[1]);
      qh_[i][kh] = asbf(r.h); ql_[i][kh] = asbf(r.l);
    }

  // ---- scores (3-pass) ----
  f32x4 sa[2][4] = {};
#pragma unroll
  for (int i = 0; i < 2; ++i)
#pragma unroll
    for (int j = 0; j < 4; ++j)
#pragma unroll
      for (int kh = 0; kh < 2; ++kh) {
        sa[i][j] = __builtin_amdgcn_mfma_f32_16x16x32_bf16(qh_[i][kh], agh[kh][j], sa[i][j], 0, 0, 0);
        sa[i][j] = __builtin_amdgcn_mfma_f32_16x16x32_bf16(qh_[i][kh], agl[kh][j], sa[i][j], 0, 0, 0);
        sa[i][j] = __builtin_amdgcn_mfma_f32_16x16x32_bf16(ql_[i][kh], agh[kh][j], sa[i][j], 0, 0, 0);
      }

  // ---- + ab, wave softmax per row (rows live in 16-lane groups) ----
  float ev[2][4][4];     // [i][j][reg]
  float lsum[2][4];      // [i][reg]
#pragma unroll
  for (int i = 0; i < 2; ++i) {
#pragma unroll
    for (int r = 0; r < 4; ++r) {
      int t = gtok0 + i * 16 + 4 * rg + r;
      const float* abp = ab + ((size_t)h * NTOK + t) * AG;
      float sv[4];
      float m = -3.4e38f;
#pragma unroll
      for (int j = 0; j < 4; ++j) {
        int a = j * 16 + fr;
        int ac = a < AG ? a : AG - 1;
        float xv = sa[i][j][r] + abp[ac];
        sv[j] = (a < AG) ? xv : -3.4e38f;
        m = fmaxf(m, sv[j]);
      }
      m = fmaxf(m, __shfl_xor(m, 1, 64));
      m = fmaxf(m, __shfl_xor(m, 2, 64));
      m = fmaxf(m, __shfl_xor(m, 4, 64));
      m = fmaxf(m, __shfl_xor(m, 8, 64));
      float l = 0.f;
#pragma unroll
      for (int j = 0; j < 4; ++j) {
        int a = j * 16 + fr;
        float e = (a < AG) ? __expf(sv[j] - m) : 0.f;
        ev[i][j][r] = e;
        l += e;
      }
      l += __shfl_xor(l, 1, 64);
      l += __shfl_xor(l, 2, 64);
      l += __shfl_xor(l, 4, 64);
      l += __shfl_xor(l, 8, 64);
      lsum[i][r] = l;
    }
  }

  // ---- store P (unnormalized e) to LDS as trunc-split bf16 hi/lo ----
#pragma unroll
  for (int i = 0; i < 2; ++i)
#pragma unroll
    for (int r = 0; r < 4; ++r) {
      int lt = woff + i * 16 + 4 * rg + r;
#pragma unroll
      for (int j = 0; j < 4; ++j) {
        int a = j * 16 + fr;
        float e = ev[i][j][r];
        uint32_t u = __float_as_uint(e);
        float res = e - __uint_as_float(u & 0xFFFF0000u);
        Phi[lt * PSTR + a] = (short)(u >> 16);
        Plo[lt * PSTR + a] = (short)(__float_as_uint(res) >> 16);
      }
    }
  __syncthreads();

  // ---- PV (3-pass): A = P rows from LDS, B = avT rows (d) ----
  const short* avhp = avThi + (size_t)bh * 4096;
  const short* avlp = avTlo + (size_t)bh * 4096;
  bf16x8 vh_[2][4], vl_[2][4];   // [khalf][j]
#pragma unroll
  for (int j = 0; j < 4; ++j)
#pragma unroll
    for (int kh = 0; kh < 2; ++kh) {
      size_t o = (size_t)(j * 16 + fr) * 64 + kh * 32 + fko;
      vh_[kh][j] = asbf(*(const short8*)(avhp + o));
      vl_[kh][j] = asbf(*(const short8*)(avlp + o));
    }
  bf16x8 ph_[2][2], pl_[2][2];   // [i][khalf]
#pragma unroll
  for (int i = 0; i < 2; ++i)
#pragma unroll
    for (int kh = 0; kh < 2; ++kh) {
      int lt = woff + i * 16 + fr;
      ph_[i][kh] = asbf(*(const short8*)&Phi[lt * PSTR + kh * 32 + fko]);
      pl_[i][kh] = asbf(*(const short8*)&Plo[lt * PSTR + kh * 32 + fko]);
    }
  f32x4 oa[2][4] = {};
#pragma unroll
  for (int i = 0; i < 2; ++i)
#pragma unroll
    for (int j = 0; j < 4; ++j)
#pragma unroll
      for (int kh = 0; kh < 2; ++kh) {
        oa[i][j] = __builtin_amdgcn_mfma_f32_16x16x32_bf16(ph_[i][kh], vh_[kh][j], oa[i][j], 0, 0, 0);
        oa[i][j] = __builtin_amdgcn_mfma_f32_16x16x32_bf16(ph_[i][kh], vl_[kh][j], oa[i][j], 0, 0, 0);
        oa[i][j] = __builtin_amdgcn_mfma_f32_16x16x32_bf16(pl_[i][kh], vh_[kh][j], oa[i][j], 0, 0, 0);
      }

  // ---- normalize + write back into q (out_pre) ----
#pragma unroll
  for (int i = 0; i < 2; ++i)
#pragma unroll
    for (int r = 0; r < 4; ++r) {
      float inv = 1.f / lsum[i][r];
      float* qp = q + (qrow0 + i * 16 + 4 * rg + r) * INNER + h * 64;
#pragma unroll
      for (int j = 0; j < 4; ++j)
        qp[j * 16 + fr] = oa[i][j][r] * inv;
    }
}

// ---------------- depthwise 3x3 conv on v (de-interleaved), added into out_pre ----------------
__global__ __launch_bounds__(256) void dwc4_kernel(const float* __restrict__ v_g,
                                                   const float* __restrict__ dwc_w,
                                                   const float* __restrict__ dwc_b,
                                                   float* __restrict__ outp) {
  int idx = blockIdx.x * 256 + threadIdx.x;    // 16*4096*128 threads
  int cq = (idx & 127) << 2;
  int r  = idx >> 7;
  int x = r & 63, y = (r >> 6) & 63, b = r >> 12;
  float wreg[36];
  {
    const float4* wp = (const float4*)(dwc_w + (size_t)cq * 9);
#pragma unroll
    for (int j = 0; j < 9; ++j) {
      float4 t = wp[j];
      wreg[4 * j + 0] = t.x; wreg[4 * j + 1] = t.y;
      wreg[4 * j + 2] = t.z; wreg[4 * j + 3] = t.w;
    }
  }
  float4 s = *(const float4*)(dwc_b + cq);
  const float* vb = v_g + (size_t)b * NTOK * 512 + cq;
#pragma unroll
  for (int ky = 0; ky < 3; ++ky) {
    int yy = y + ky - 1;
    if (yy < 0 || yy > 63) continue;
#pragma unroll
    for (int kx = 0; kx < 3; ++kx) {
      int xx = x + kx - 1;
      if (xx < 0 || xx > 63) continue;
      float4 v4 = *(const float4*)(vb + (size_t)(yy * 64 + xx) * 512);
      const int t = ky * 3 + kx;
      s.x = fmaf(wreg[0 * 9 + t], v4.x, s.x);
      s.y = fmaf(wreg[1 * 9 + t], v4.y, s.y);
      s.z = fmaf(wreg[2 * 9 + t], v4.z, s.z);
      s.w = fmaf(wreg[3 * 9 + t], v4.w, s.w);
    }
  }
  size_t o = (size_t)r * INNER + cq;
  float4 cur = *(const float4*)(outp + o);
  cur.x += s.x; cur.y += s.y; cur.z += s.z; cur.w += s.w;
  *(float4*)(outp + o) = cur;
}

// ---------------- host launcher ----------------
extern "C" void kernel_launch(void* const* d_in, const int* in_sizes, int n_in,
                              void* d_out, int out_size, void* d_ws, size_t ws_size,
                              hipStream_t stream) {
  const float* x       = (const float*)d_in[0];
  const float* context = (const float*)d_in[1];
  const float* q_w     = (const float*)d_in[2];
  const float* kv_w    = (const float*)d_in[3];
  const float* proj_w  = (const float*)d_in[4];
  const float* proj_b  = (const float*)d_in[5];
  const float* conv_w  = (const float*)d_in[6];
  const float* conv_b  = (const float*)d_in[7];
  const float* dwc_w   = (const float*)d_in[8];
  const float* dwc_b   = (const float*)d_in[9];
  const float* an_bias = (const float*)d_in[10];
  const float* na_bias = (const float*)d_in[11];
  const float* ah_bias = (const float*)d_in[12];
  const float* aw_bias = (const float*)d_in[13];
  const float* ha_bias = (const float*)d_in[14];
  const float* wa_bias = (const float*)d_in[15];
  float* out = (float*)d_out;
  float* wsf = (float*)d_ws;

  float* q_buf  = wsf + Q_OFF;    // later becomes out_pre
  float* k_buf  = wsf + KV_OFF;                              // de-interleaved k: 512-float rows
  float* v_buf  = wsf + KV_OFF + (size_t)BB * NTOK * INNER;  // de-interleaved v
  float* A2     = wsf + A2_OFF;
  float* Col    = wsf + COL_OFF;
  float* Cg     = wsf + CG_OFF;
  float* agent  = wsf + AGT_OFF;
  float* pb     = wsf + PB_OFF;
  float* ab     = wsf + AB_OFF;
  float* pnum   = wsf + PNUM_OFF;  // overlays Col (retired by then)
  float* pl     = wsf + PL_OFF;
  short* avThi  = (short*)(wsf + AVT_OFF);
  short* avTlo  = avThi + (size_t)128 * 64 * 64;
  short* whi    = (short*)(wsf + WSP_OFF);      // rows 0..511 q_w, 512..1535 kv_w, 1536..2047 proj_w
  short* wlo    = whi + (size_t)2048 * 512;
  float* S1q    = wsf + COL_OFF;   // pool scratch (COL region, free until im2col)
  float* S1c    = wsf + CG_OFF;    // pool scratch (CG.. regions, free until conv)

  const int M = BB * NTOK;   // 65536

  // 0. one-time weight splits (fp32 -> bf16 hi/lo)
  split_w_kernel<<<(512 * 512 / 8 + 255) / 256, 256, 0, stream>>>(q_w, whi, wlo, 512 * 512 / 8);
  split_w_kernel<<<(1024 * 512 / 8 + 255) / 256, 256, 0, stream>>>(kv_w, whi + (size_t)512 * 512, wlo + (size_t)512 * 512, 1024 * 512 / 8);
  split_w_kernel<<<(512 * 512 / 8 + 255) / 256, 256, 0, stream>>>(proj_w, whi + (size_t)1536 * 512, wlo + (size_t)1536 * 512, 512 * 512 / 8);

  // 1. fused [q|k|v] = x @ [q_w|kv_w]^T  (MFMA split-bf16, pre-split B, XCD swizzle; 3-way epilogue)
  gemm_ws3<false><<<dim3(1536 / 128, M / 128), 256, 0, stream>>>(x, whi, wlo, nullptr,
                                                                 q_buf, k_buf, v_buf, M, DIMC);
  // 3. separable pooled concat
  pool_h_kernel<<<(BB * 7 * 64 * 768) / 256, 256, 0, stream>>>(q_buf, context, S1q, S1c);
  pool_w_kernel<<<(BB * AG * 768 + 255) / 256, 256, 0, stream>>>(S1q, S1c, A2);
  // 4. im2col
  im2col_kernel<<<(784 * 6912 + 255) / 256, 256, 0, stream>>>(A2, Col);
  // 5. conv as GEMM, split-K with atomics (zero Cg first)
  zero_kernel<<<(784 * INNER + 255) / 256, 256, 0, stream>>>(Cg, 784 * INNER);
  conv_gemm_splitk<<<dim3(INNER / 64, (784 + 63) / 64, CKS), 256, 0, stream>>>(Col, conv_w, Cg);
  // 6. scramble + conv bias -> agent[b,h,a,d]
  agent_scatter_kernel<<<(BB * HEADS * AG * HD + 255) / 256, 256, 0, stream>>>(Cg, conv_b, agent);
  // 7./8. bias tables
  pb_kernel<<<(HEADS * AG * NTOK + 255) / 256, 256, 0, stream>>>(an_bias, ah_bias, aw_bias, pb);
  ab_kernel<<<(HEADS * NTOK * AG + 255) / 256, 256, 0, stream>>>(na_bias, ha_bias, wa_bias, ab);
  // 9. agent attention via MFMA -> partials -> avT (transposed, bf16-split agent_v)
  agent_attn_mfma<<<dim3(ASPLIT, HEADS, BB), 256, 0, stream>>>(k_buf, v_buf, agent, pb, pnum, pl);
  agent_attn_combine<<<(128 * 64 * 64) / 256, 256, 0, stream>>>(pnum, pl, avThi, avTlo);
  // 10. q attention via MFMA (q_buf overwritten with out_pre)
  q_attn_mfma<<<dim3(NTOK / 128, HEADS, BB), 256, 0, stream>>>(agent, avThi, avTlo, ab, q_buf);
  // 11. depthwise conv on v added into out_pre (vectorized: 4 ch/thread, dense v rows)
  dwc4_kernel<<<(BB * NTOK * 128) / 256, 256, 0, stream>>>(v_buf, dwc_w, dwc_b, q_buf);
  // 12. final projection with bias (MFMA, XCD swizzle)
  gemm_ws3<true><<<dim3(DIMC / 128, M / 128), 256, 0, stream>>>(q_buf, whi + (size_t)1536 * 512, wlo + (size_t)1536 * 512,
                                                                proj_b, out, out, out, M, INNER);

  (void)in_sizes; (void)n_in; (void)out_size; (void)ws_size;
}

// Round 11
// 1400.266 us; speedup vs baseline: 1.0041x; 1.0041x over previous
//
#include <hip/hip_runtime.h>
#include <cstdint>
#include <cstddef>

// Problem constants (fixed by setup_inputs)
#define BB    16
#define NTOK  4096
#define DIMC  512
#define INNER 512
#define CTXC  256
#define HEADS 8
#define HD    64
#define AG    49
#define ASPLIT 8   // n-splits for agent attention
#define CONVK 6912
#define CKS   16   // k-splits for conv GEMM (chunk = 432 = 27*16)

// ---------------- workspace layout (floats) ----------------
static const size_t Q_OFF   = 0;                                     // q / out_pre: 16*4096*512
static const size_t KV_OFF  = Q_OFF  + (size_t)BB*NTOK*INNER;        // k_buf: 16*4096*512, then v_buf: 16*4096*512
static const size_t A2_OFF  = KV_OFF + (size_t)BB*NTOK*2*INNER;      // pooled concat: 16*49*768
static const size_t COL_OFF = A2_OFF + (size_t)BB*AG*768;            // im2col: 784*6912 (pool S1q scratch before; attn partials + avT after)
static const size_t CG_OFF  = COL_OFF+ (size_t)BB*AG*768*9;          // conv gemm out: 784*512 (pool S1c scratch)
static const size_t AGT_OFF = CG_OFF + (size_t)BB*AG*INNER;          // agent[b,h,a,d]
static const size_t AGV_OFF = AGT_OFF+ (size_t)BB*HEADS*AG*HD;       // (retired)
static const size_t PB_OFF  = AGV_OFF+ (size_t)BB*HEADS*AG*HD;       // pb[h,a,n]
static const size_t AB_OFF  = PB_OFF + (size_t)HEADS*AG*NTOK;        // ab[h,n,a]
static const size_t WSP_OFF = AB_OFF + (size_t)HEADS*NTOK*AG;        // pre-split weights: 2*2048*512 shorts = 1,048,576 floats
// overlays of the retired COL region:
static const size_t PNUM_OFF = COL_OFF;                              // 8*128*64*64 = 4,194,304 floats
static const size_t PL_OFF   = PNUM_OFF + (size_t)ASPLIT*128*64*64;  // 8*128*64    = 65,536 floats
static const size_t AVT_OFF  = PL_OFF + (size_t)ASPLIT*128*64;       // avT hi/lo: 2*128*64*64 shorts = 524,288 floats
// (4,259,840 + 524,288 = 4,784,128 < COL region's 5,419,008 floats)

typedef __attribute__((ext_vector_type(8))) short  short8;   // 8 bf16 bit-patterns (4 VGPRs)
typedef __attribute__((ext_vector_type(8))) __bf16 bf16x8;   // canonical MFMA operand type
typedef __attribute__((ext_vector_type(4))) float  f32x4;    // MFMA accumulator

union SB8 { short8 s; bf16x8 b; };

__device__ inline bf16x8 asbf(short8 v) { SB8 u; u.s = v; return u.b; }

// round-to-nearest-even fp32 -> bf16 bits
__device__ inline unsigned short bfrn(float x) {
  uint32_t u = __float_as_uint(x);
  return (unsigned short)((u + 0x7FFFu + ((u >> 16) & 1u)) >> 16);
}

struct HL8 { short8 h, l; };

// split 8 fp32 into bf16 hi (RNE) + bf16 lo (RNE) — used once for weights
__device__ inline HL8 split8(float4 f0, float4 f1) {
  HL8 r;
  float v0[4] = {f0.x, f0.y, f0.z, f0.w};
  float v1[4] = {f1.x, f1.y, f1.z, f1.w};
#pragma unroll
  for (int j = 0; j < 4; ++j) {
    unsigned short hb = bfrn(v0[j]);
    r.h[j] = (short)hb;
    r.l[j] = (short)bfrn(v0[j] - __uint_as_float((uint32_t)hb << 16));
  }
#pragma unroll
  for (int j = 0; j < 4; ++j) {
    unsigned short hb = bfrn(v1[j]);
    r.h[j + 4] = (short)hb;
    r.l[j + 4] = (short)bfrn(v1[j] - __uint_as_float((uint32_t)hb << 16));
  }
  return r;
}

// TRUNC-TRUNC split: hi=trunc(v), lo=trunc(v-hi). v-hi is EXACT (same exponent),
// so hi+lo reconstruction error <= 2^-16|v| — same as RNE-hi, at ~half the VALU ops.
__device__ inline HL8 split8t(float4 f0, float4 f1) {
  HL8 r;
  float v[8] = {f0.x, f0.y, f0.z, f0.w, f1.x, f1.y, f1.z, f1.w};
#pragma unroll
  for (int j = 0; j < 8; ++j) {
    uint32_t u = __float_as_uint(v[j]);
    r.h[j] = (short)(u >> 16);
    float res = v[j] - __uint_as_float(u & 0xFFFF0000u);
    r.l[j] = (short)(__float_as_uint(res) >> 16);
  }
  return r;
}

// ---------------- one-time weight split: fp32 -> bf16 hi/lo ----------------
__global__ void split_w_kernel(const float* __restrict__ src, short* __restrict__ dhi,
                               short* __restrict__ dlo, int n8) {
  int i = blockIdx.x * 256 + threadIdx.x;
  if (i >= n8) return;
  const float4* s = (const float4*)src + (size_t)i * 2;
  HL8 r = split8(s[0], s[1]);
  *(short8*)(dhi + (size_t)i * 8) = r.h;
  *(short8*)(dlo + (size_t)i * 8) = r.l;
}

// ---------------- MFMA split-bf16 GEMM, 128x128 tile: [C1|C2|C3] = A(MxK) * Bw^T (+bias) ----------------
// 3-pass hi/lo split: C = Ah*Bh + Ah*Bl + Al*Bh. B pre-split bf16.
// XCD-aware block swizzle (nwg % 8 == 0). Output col-tile t = bnT>>9 routes to C1/C2/C3 (each 512 wide).
// LDS row stride 40 (R6 config). __launch_bounds__(256,6) pins VGPR<=84 -> 6 waves/SIMD
// (R10 lesson: 88 VGPR -> 5 waves/SIMD occupancy cliff cost +64us; same cliff caused the R7 regression).
#define LSTR 40
template <bool ADD_BIAS>
__global__ __launch_bounds__(256, 6) void gemm_ws3(const float* __restrict__ A,
                                                   const short* __restrict__ Bhi_g,
                                                   const short* __restrict__ Blo_g,
                                                   const float* __restrict__ bias,
                                                   float* __restrict__ C1,
                                                   float* __restrict__ C2,
                                                   float* __restrict__ C3,
                                                   int M, int K) {
  __shared__ short Ahi[128 * LSTR];
  __shared__ short Alo[128 * LSTR];
  __shared__ short Bhi[128 * LSTR];
  __shared__ short Blo[128 * LSTR];
  const int tid  = threadIdx.x;
  const int lane = tid & 63;
  const int wave = tid >> 6;
  const int wm = wave >> 1, wn = wave & 1;          // 2x2 wave grid
  // XCD-aware swizzle: consecutive blocks within an XCD share an A m-panel
  const int nwg = gridDim.x * gridDim.y;
  const int lin = blockIdx.y * gridDim.x + blockIdx.x;
  const int swz = (lin & 7) * (nwg >> 3) + (lin >> 3);
  const int bx = swz % gridDim.x, by = swz / gridDim.x;
  const int bm = by * 128, bnT = bx * 128;
  // staging role: 2 threads per row, 16 consecutive k each
  const int srow  = tid >> 1;
  const int shalf = (tid & 1) << 4;                 // 0 or 16 (elements)
  // fragment role
  const int fr  = lane & 15;                        // row/col within 16x16 frag
  const int fko = (lane >> 4) << 3;                 // k offset: 0,8,16,24

  f32x4 acc[4][4] = {};

  for (int k0 = 0; k0 < K; k0 += 32) {
    {
      // A: fp32 load + in-kernel trunc-trunc split
      const float4* ap = (const float4*)(A + (size_t)(bm + srow) * K + k0 + shalf);
      float4 a0 = ap[0], a1 = ap[1], a2 = ap[2], a3 = ap[3];
      HL8 r0 = split8t(a0, a1);
      *(short8*)&Ahi[srow * LSTR + shalf] = r0.h;
      *(short8*)&Alo[srow * LSTR + shalf] = r0.l;
      HL8 r1 = split8t(a2, a3);
      *(short8*)&Ahi[srow * LSTR + shalf + 8] = r1.h;
      *(short8*)&Alo[srow * LSTR + shalf + 8] = r1.l;
      // B: pre-split bf16, straight copy to LDS
      const short* bhp = Bhi_g + (size_t)(bnT + srow) * K + k0 + shalf;
      *(short8*)&Bhi[srow * LSTR + shalf]     = *(const short8*)bhp;
      *(short8*)&Bhi[srow * LSTR + shalf + 8] = *(const short8*)(bhp + 8);
      const short* blp = Blo_g + (size_t)(bnT + srow) * K + k0 + shalf;
      *(short8*)&Blo[srow * LSTR + shalf]     = *(const short8*)blp;
      *(short8*)&Blo[srow * LSTR + shalf + 8] = *(const short8*)(blp + 8);
    }
    __syncthreads();
    bf16x8 ah[4], al[4], bh[4], bl[4];
#pragma unroll
    for (int i = 0; i < 4; ++i) {
      int ra = wm * 64 + i * 16 + fr;
      ah[i] = asbf(*(const short8*)&Ahi[ra * LSTR + fko]);
      al[i] = asbf(*(const short8*)&Alo[ra * LSTR + fko]);
      int rb = wn * 64 + i * 16 + fr;
      bh[i] = asbf(*(const short8*)&Bhi[rb * LSTR + fko]);
      bl[i] = asbf(*(const short8*)&Blo[rb * LSTR + fko]);
    }
#pragma unroll
    for (int i = 0; i < 4; ++i)
#pragma unroll
      for (int j = 0; j < 4; ++j) {
        acc[i][j] = __builtin_amdgcn_mfma_f32_16x16x32_bf16(ah[i], bh[j], acc[i][j], 0, 0, 0);
        acc[i][j] = __builtin_amdgcn_mfma_f32_16x16x32_bf16(ah[i], bl[j], acc[i][j], 0, 0, 0);
        acc[i][j] = __builtin_amdgcn_mfma_f32_16x16x32_bf16(al[i], bh[j], acc[i][j], 0, 0, 0);
      }
    __syncthreads();
  }

  // epilogue: C/D layout col=lane&15, row=4*(lane>>4)+reg; route to C1/C2/C3 (512 cols each)
  const int crow0 = wm * 64 + ((lane >> 4) << 2);
  const int ccol0 = wn * 64 + fr;
  const int t = bnT >> 9;
  float* Cb = (t == 0) ? C1 : (t == 1) ? C2 : C3;
  const int coff = bnT & 511;
  float bs[4];
  if (ADD_BIAS) {
#pragma unroll
    for (int j = 0; j < 4; ++j) bs[j] = bias[bnT + ccol0 + j * 16];
  }
#pragma unroll
  for (int i = 0; i < 4; ++i) {
#pragma unroll
    for (int r = 0; r < 4; ++r) {
      size_t row = (size_t)(bm + crow0 + i * 16 + r);
      float* cp = Cb + row * 512 + coff + ccol0;
#pragma unroll
      for (int j = 0; j < 4; ++j) {
        float v = acc[i][j][r];
        if (ADD_BIAS) v += bs[j];
        cp[j * 16] = v;
      }
    }
  }
}

// ---------------- zero-fill (graph-capture-safe memset) ----------------
__global__ void zero_kernel(float* __restrict__ p, int n) {
  int i = blockIdx.x * 256 + threadIdx.x;
  if (i < n) p[i] = 0.f;
}

// ---------------- conv GEMM, split-K + atomics: Cg[784][512] += Col[784][6912] @ W[512][6912]^T ----------------
__global__ __launch_bounds__(256) void conv_gemm_splitk(const float* __restrict__ A,
                                                        const float* __restrict__ Bw,
                                                        float* __restrict__ C) {
  __shared__ float As[16][72];
  __shared__ float Bs[16][72];
  const int tid = threadIdx.x;
  const int tx = tid & 15, ty = tid >> 4;
  const int bn = blockIdx.x * 64;
  const int bm = blockIdx.y * 64;
  const int k_begin = blockIdx.z * (CONVK / CKS);
  const int k_end = k_begin + (CONVK / CKS);
  const int row = tid >> 2, c4 = (tid & 3) << 2;
  float acc[4][4] = {};
  for (int k0 = k_begin; k0 < k_end; k0 += 16) {
    {
      int m = bm + row;
      float4 av = {0.f, 0.f, 0.f, 0.f};
      if (m < 784) av = *(const float4*)(A + (size_t)m * CONVK + k0 + c4);
      As[c4 + 0][row] = av.x; As[c4 + 1][row] = av.y;
      As[c4 + 2][row] = av.z; As[c4 + 3][row] = av.w;
      float4 bv = *(const float4*)(Bw + (size_t)(bn + row) * CONVK + k0 + c4);
      Bs[c4 + 0][row] = bv.x; Bs[c4 + 1][row] = bv.y;
      Bs[c4 + 2][row] = bv.z; Bs[c4 + 3][row] = bv.w;
    }
    __syncthreads();
#pragma unroll
    for (int k = 0; k < 16; ++k) {
      float a[4], b[4];
#pragma unroll
      for (int i = 0; i < 4; ++i) a[i] = As[k][ty * 4 + i];
#pragma unroll
      for (int j = 0; j < 4; ++j) b[j] = Bs[k][tx * 4 + j];
#pragma unroll
      for (int i = 0; i < 4; ++i)
#pragma unroll
        for (int j = 0; j < 4; ++j) acc[i][j] = fmaf(a[i], b[j], acc[i][j]);
    }
    __syncthreads();
  }
#pragma unroll
  for (int i = 0; i < 4; ++i) {
    int m = bm + ty * 4 + i;
    if (m >= 784) continue;
#pragma unroll
    for (int j = 0; j < 4; ++j)
      atomicAdd(C + (size_t)m * INNER + bn + tx * 4 + j, acc[i][j]);
  }
}

// ---------------- separable overlapping avg-pool, stage 1: pool over h ----------------
__global__ void pool_h_kernel(const float* __restrict__ q, const float* __restrict__ ctx,
                              float* __restrict__ S1q, float* __restrict__ S1c) {
  int idx = blockIdx.x * 256 + threadIdx.x;    // 16*7*64*768
  if (idx >= BB * 7 * 64 * 768) return;
  int c  = idx % 768;
  int w  = (idx / 768) & 63;
  int ph = (idx / (768 * 64)) % 7;
  int b  = idx / (768 * 64 * 7);
  int hs = ph * 64 / 7, he = ((ph + 1) * 64 + 6) / 7;
  float s = 0.f;
  if (c < 512) {
    const float* p = q + ((size_t)b * NTOK + hs * 64 + w) * INNER + c;
    for (int h = hs; h < he; ++h) { s += *p; p += 64 * INNER; }
    S1q[((size_t)(b * 7 + ph) * 64 + w) * 512 + c] = s;
  } else {
    int cc = c - 512;
    const float* p = ctx + ((size_t)b * NTOK + hs * 64 + w) * CTXC + cc;
    for (int h = hs; h < he; ++h) { s += *p; p += 64 * CTXC; }
    S1c[((size_t)(b * 7 + ph) * 64 + w) * 256 + cc] = s;
  }
}

// ---------------- pool stage 2: pool over w, normalize -> A2[b,49,768] ----------------
__global__ void pool_w_kernel(const float* __restrict__ S1q, const float* __restrict__ S1c,
                              float* __restrict__ A2) {
  int idx = blockIdx.x * 256 + threadIdx.x;    // 16*49*768
  if (idx >= BB * AG * 768) return;
  int c = idx % 768;
  int p = (idx / 768) % AG;
  int b = idx / (768 * AG);
  int i = p / 7, j = p % 7;
  int hs = i * 64 / 7, he = ((i + 1) * 64 + 6) / 7;
  int ws = j * 64 / 7, we = ((j + 1) * 64 + 6) / 7;
  float inv = 1.f / (float)((he - hs) * (we - ws));
  float s = 0.f;
  if (c < 512) {
    const float* pp = S1q + ((size_t)(b * 7 + i) * 64 + ws) * 512 + c;
    for (int w = ws; w < we; ++w) { s += *pp; pp += 512; }
  } else {
    const float* pp = S1c + ((size_t)(b * 7 + i) * 64 + ws) * 256 + (c - 512);
    for (int w = ws; w < we; ++w) { s += *pp; pp += 256; }
  }
  A2[((size_t)b * AG + p) * 768 + c] = s * inv;
}

// ---------------- im2col of scrambled agent_in: Col[b*49+p][ic*9+ky*3+kx] ----------------
__global__ void im2col_kernel(const float* __restrict__ A2, float* __restrict__ Col) {
  int idx = blockIdx.x * 256 + threadIdx.x;    // 784*6912
  if (idx >= 784 * 6912) return;
  int r = idx / 6912, t = idx % 6912;
  int ic = t / 9, ky = (t % 9) / 3, kx = t % 3;
  int b = r / AG, p = r % AG;
  int y = p / 7 + ky - 1, x = p % 7 + kx - 1;
  float v = 0.f;
  if (y >= 0 && y < 7 && x >= 0 && x < 7) {
    int g = ic * 49 + y * 7 + x;
    v = A2[((size_t)b * AG + g / 768) * 768 + (g % 768)];
  }
  Col[(size_t)idx] = v;
}

// ---------------- scramble conv output -> agent[b,h,a,d] (+conv bias) ----------------
__global__ void agent_scatter_kernel(const float* __restrict__ Cg, const float* __restrict__ conv_b,
                                     float* __restrict__ agent) {
  int idx = blockIdx.x * 256 + threadIdx.x;   // 16*8*49*64
  if (idx >= BB * HEADS * AG * HD) return;
  int d = idx & 63;
  int a = (idx >> 6) % AG;
  int h = (idx / (64 * AG)) % HEADS;
  int b = idx / (64 * AG * HEADS);
  int f = a * 512 + h * 64 + d;
  int oc = f / 49, p = f % 49;
  agent[idx] = Cg[((size_t)b * AG + p) * INNER + oc] + conv_b[oc];
}

// ---------------- jax bilinear resize 7->64 (half-pixel, renorm == clamp) ----------------
__device__ inline float bilinear7(const float* __restrict__ Bm, int y, int x) {
  float fy = (y + 0.5f) * (7.f / 64.f) - 0.5f;
  float fx = (x + 0.5f) * (7.f / 64.f) - 0.5f;
  fy = fminf(fmaxf(fy, 0.f), 6.f);
  fx = fminf(fmaxf(fx, 0.f), 6.f);
  int y0 = min((int)floorf(fy), 5);
  int x0 = min((int)floorf(fx), 5);
  float ty = fy - y0, tx = fx - x0;
  float v00 = Bm[y0 * 7 + x0],     v01 = Bm[y0 * 7 + x0 + 1];
  float v10 = Bm[(y0 + 1) * 7 + x0], v11 = Bm[(y0 + 1) * 7 + x0 + 1];
  return (1.f - ty) * ((1.f - tx) * v00 + tx * v01) + ty * ((1.f - tx) * v10 + tx * v11);
}

// pb[h][a][n] = resize(an_bias[h,a])(y,x) + ah[h,a,y] + aw[h,a,x]
__global__ void pb_kernel(const float* __restrict__ an_bias, const float* __restrict__ ah,
                          const float* __restrict__ aw, float* __restrict__ pb) {
  int idx = blockIdx.x * 256 + threadIdx.x;   // 8*49*4096
  if (idx >= HEADS * AG * NTOK) return;
  int nn = idx & (NTOK - 1);
  int a = (idx / NTOK) % AG;
  int h = idx / (NTOK * AG);
  int y = nn >> 6, x = nn & 63;
  float v = bilinear7(an_bias + ((size_t)h * AG + a) * 49, y, x);
  v += ah[((size_t)h * AG + a) * 64 + y] + aw[((size_t)h * AG + a) * 64 + x];
  pb[idx] = v;
}

// ab[h][n][a] = resize(na_bias[h,a])(y,x) + ha[h,y,a] + wa[h,x,a]
__global__ void ab_kernel(const float* __restrict__ na_bias, const float* __restrict__ ha,
                          const float* __restrict__ wa, float* __restrict__ ab) {
  int idx = blockIdx.x * 256 + threadIdx.x;   // 8*4096*49
  if (idx >= HEADS * NTOK * AG) return;
  int a = idx % AG;
  int nn = (idx / AG) & (NTOK - 1);
  int h = idx / (AG * NTOK);
  int y = nn >> 6, x = nn & 63;
  float v = bilinear7(na_bias + ((size_t)h * AG + a) * 49, y, x);
  v += ha[((size_t)h * 64 + y) * AG + a] + wa[((size_t)h * 64 + x) * AG + a];
  ab[idx] = v;
}

// ---------------- agent attention via MFMA (split-bf16 3-pass QK^T and PV) ----------------
// k_buf/v_buf are de-interleaved (512-float rows).
#define ESTR 72
__global__ __launch_bounds__(256, 2) void agent_attn_mfma(const float* __restrict__ k_g,
                                                          const float* __restrict__ v_g,
                                                          const float* __restrict__ agent,
                                                          const float* __restrict__ pb,
                                                          float* __restrict__ part_num,
                                                          float* __restrict__ part_l) {
  const int split = blockIdx.x;                 // 0..ASPLIT-1
  const int h = blockIdx.y, b = blockIdx.z;
  const int bh = b * HEADS + h;
  __shared__ short eThi[64 * ESTR];
  __shared__ short eTlo[64 * ESTR];
  __shared__ short vThi[64 * ESTR];
  __shared__ short vTlo[64 * ESTR];
  __shared__ float lred[4][64];
  const int tid = threadIdx.x;
  const int lane = tid & 63;
  const int w = tid >> 6;                       // wave id
  const int fr = lane & 15;
  const int fko = (lane >> 4) << 3;             // 0,8,16,24
  const int rg = lane >> 4;                     // C-layout row group

  // ---- persistent A-frags: agent rows a=i*16+fr (clamped; masked later), scaled 0.125, split ----
  bf16x8 agh[4][2], agl[4][2];
#pragma unroll
  for (int i = 0; i < 4; ++i) {
    int ar = i * 16 + fr; if (ar > AG - 1) ar = AG - 1;
#pragma unroll
    for (int kh = 0; kh < 2; ++kh) {
      const float4* p = (const float4*)(agent + ((size_t)bh * AG + ar) * HD + kh * 32 + fko);
      float4 f0 = p[0], f1 = p[1];
      f0.x *= 0.125f; f0.y *= 0.125f; f0.z *= 0.125f; f0.w *= 0.125f;
      f1.x *= 0.125f; f1.y *= 0.125f; f1.z *= 0.125f; f1.w *= 0.125f;
      HL8 r = split8t(f0, f1);
      agh[i][kh] = asbf(r.h); agl[i][kh] = asbf(r.l);
    }
  }

  float lacc[4][4] = {};       // [i][reg] per-lane l partials (this lane's n column)
  f32x4 oa[4] = {};            // PV acc: rows a=i*16+4rg+reg, col d=w*16+fr

  const float* kb = k_g + (size_t)b * NTOK * 512 + h * 64;   // k rows, stride 512
  const float* vb = v_g + (size_t)b * NTOK * 512 + h * 64;   // v rows, stride 512
  const float* pbh = pb + (size_t)h * AG * NTOK;
  const int nrow = tid & 63, dq = tid >> 6;                   // vT staging mapping

  for (int c = 0; c < 8; ++c) {
    const int n0 = split * 512 + c * 64;
    // ---- stage vT[d][n] split-bf16 ----
    {
      const float* vr = vb + (size_t)(n0 + nrow) * 512;
#pragma unroll
      for (int p = 0; p < 2; ++p) {
        int d0 = dq * 16 + p * 8;
        float4 f0 = *(const float4*)(vr + d0);
        float4 f1 = *(const float4*)(vr + d0 + 4);
        HL8 r = split8t(f0, f1);
#pragma unroll
        for (int j = 0; j < 8; ++j) {
          vThi[(d0 + j) * ESTR + nrow] = r.h[j];
          vTlo[(d0 + j) * ESTR + nrow] = r.l[j];
        }
      }
    }
    // ---- QK: B-frags from k row n = n0 + w*16 + fr ----
    bf16x8 kh_[2], kl_[2];
    {
      const float* kr = kb + (size_t)(n0 + w * 16 + fr) * 512;
#pragma unroll
      for (int kh = 0; kh < 2; ++kh) {
        float4 f0 = *(const float4*)(kr + kh * 32 + fko);
        float4 f1 = *(const float4*)(kr + kh * 32 + fko + 4);
        HL8 r = split8t(f0, f1);
        kh_[kh] = asbf(r.h); kl_[kh] = asbf(r.l);
      }
    }
    f32x4 sa[4] = {};
#pragma unroll
    for (int i = 0; i < 4; ++i)
#pragma unroll
      for (int kh = 0; kh < 2; ++kh) {
        sa[i] = __builtin_amdgcn_mfma_f32_16x16x32_bf16(agh[i][kh], kh_[kh], sa[i], 0, 0, 0);
        sa[i] = __builtin_amdgcn_mfma_f32_16x16x32_bf16(agh[i][kh], kl_[kh], sa[i], 0, 0, 0);
        sa[i] = __builtin_amdgcn_mfma_f32_16x16x32_bf16(agl[i][kh], kh_[kh], sa[i], 0, 0, 0);
      }
    // ---- e = exp(s + pb) masked; accumulate l; write trunc-split e to eT ----
    const int ncol = n0 + w * 16 + fr;
#pragma unroll
    for (int i = 0; i < 4; ++i)
#pragma unroll
      for (int r = 0; r < 4; ++r) {
        int a = i * 16 + 4 * rg + r;
        float e = 0.f;
        if (a < AG) e = __expf(sa[i][r] + pbh[(size_t)a * NTOK + ncol]);
        lacc[i][r] += e;
        uint32_t u = __float_as_uint(e);
        float res = e - __uint_as_float(u & 0xFFFF0000u);
        eThi[a * ESTR + w * 16 + fr] = (short)(u >> 16);
        eTlo[a * ESTR + w * 16 + fr] = (short)(__float_as_uint(res) >> 16);
      }
    __syncthreads();
    // ---- PV: A = eT rows, B = vT rows d = w*16+fr ----
    bf16x8 vh_[2], vl_[2];
#pragma unroll
    for (int kh = 0; kh < 2; ++kh) {
      vh_[kh] = asbf(*(const short8*)&vThi[(w * 16 + fr) * ESTR + kh * 32 + fko]);
      vl_[kh] = asbf(*(const short8*)&vTlo[(w * 16 + fr) * ESTR + kh * 32 + fko]);
    }
#pragma unroll
    for (int i = 0; i < 4; ++i)
#pragma unroll
      for (int kh = 0; kh < 2; ++kh) {
        bf16x8 eh = asbf(*(const short8*)&eThi[(i * 16 + fr) * ESTR + kh * 32 + fko]);
        bf16x8 el = asbf(*(const short8*)&eTlo[(i * 16 + fr) * ESTR + kh * 32 + fko]);
        oa[i] = __builtin_amdgcn_mfma_f32_16x16x32_bf16(eh, vh_[kh], oa[i], 0, 0, 0);
        oa[i] = __builtin_amdgcn_mfma_f32_16x16x32_bf16(eh, vl_[kh], oa[i], 0, 0, 0);
        oa[i] = __builtin_amdgcn_mfma_f32_16x16x32_bf16(el, vh_[kh], oa[i], 0, 0, 0);
      }
    __syncthreads();
  }

  // ---- l: reduce over fr (16-lane groups), then across waves via LDS ----
#pragma unroll
  for (int i = 0; i < 4; ++i)
#pragma unroll
    for (int r = 0; r < 4; ++r) {
      float l = lacc[i][r];
      l += __shfl_xor(l, 1, 64); l += __shfl_xor(l, 2, 64);
      l += __shfl_xor(l, 4, 64); l += __shfl_xor(l, 8, 64);
      lacc[i][r] = l;
    }
  if (fr == 0) {
#pragma unroll
    for (int i = 0; i < 4; ++i)
#pragma unroll
      for (int r = 0; r < 4; ++r)
        lred[w][i * 16 + 4 * rg + r] = lacc[i][r];
  }
  __syncthreads();

  float* pn = part_num + ((size_t)(split * 128 + bh)) * 64 * 64;
  float* pl = part_l + (size_t)(split * 128 + bh) * 64;
#pragma unroll
  for (int i = 0; i < 4; ++i)
#pragma unroll
    for (int r = 0; r < 4; ++r) {
      int a = i * 16 + 4 * rg + r;
      if (a < AG) pn[a * 64 + w * 16 + fr] = oa[i][r];
    }
  if (tid < AG) pl[tid] = lred[0][tid] + lred[1][tid] + lred[2][tid] + lred[3][tid];
}

// ---------------- combine partials -> transposed, split agent_v: avT[bh][d][a] bf16 hi/lo ----------------
__global__ void agent_attn_combine(const float* __restrict__ part_num,
                                   const float* __restrict__ part_l,
                                   short* __restrict__ avThi, short* __restrict__ avTlo) {
  int idx = blockIdx.x * 256 + threadIdx.x;   // 128*64*64
  if (idx >= 128 * 64 * 64) return;
  int a = idx & 63;
  int d = (idx >> 6) & 63;
  int bh = idx >> 12;
  float v = 0.f;
  if (a < AG) {
    float num = 0.f, l = 0.f;
#pragma unroll
    for (int s = 0; s < ASPLIT; ++s) {
      num += part_num[((size_t)(s * 128 + bh)) * 4096 + a * 64 + d];
      l += part_l[(size_t)(s * 128 + bh) * 64 + a];
    }
    v = num / l;
  }
  unsigned short hb = bfrn(v);
  float res = v - __uint_as_float((uint32_t)hb << 16);
  avThi[(size_t)bh * 4096 + d * 64 + a] = (short)hb;
  avTlo[(size_t)bh * 4096 + d * 64 + a] = (short)(__float_as_uint(res) >> 16);
}

// ---------------- q attention via MFMA: softmax_a(q*scale . agent^T + ab) @ agent_v ----------------
#define PSTR 80
__global__ __launch_bounds__(256) void q_attn_mfma(const float* __restrict__ agent,
                                                   const short* __restrict__ avThi,
                                                   const short* __restrict__ avTlo,
                                                   const float* __restrict__ ab,
                                                   float* __restrict__ q) {
  const int tile = blockIdx.x;   // 32 tiles of 128 tokens
  const int h = blockIdx.y, b = blockIdx.z;
  const int bh = b * HEADS + h;
  __shared__ short Phi[128 * PSTR];
  __shared__ short Plo[128 * PSTR];
  const int tid = threadIdx.x;
  const int lane = tid & 63;
  const int wave = tid >> 6;
  const int woff = wave * 32;          // token offset within tile
  const int fr = lane & 15;
  const int fko = (lane >> 4) << 3;    // 0,8,16,24
  const int rg = lane >> 4;            // C-layout row group

  const size_t agbase = (size_t)bh * AG * HD;
  const int gtok0 = tile * 128 + woff;              // token within [0,4096)
  const size_t qrow0 = (size_t)b * NTOK + gtok0;    // global q row of wave

  // ---- B-frags from agent rows (a = j*16+fr clamped), scaled 0.125, split in-register ----
  bf16x8 agh[2][4], agl[2][4];   // [khalf][j]
#pragma unroll
  for (int j = 0; j < 4; ++j) {
    int ar = j * 16 + fr; if (ar > AG - 1) ar = AG - 1;
#pragma unroll
    for (int kh = 0; kh < 2; ++kh) {
      const float4* p = (const float4*)(agent + agbase + (size_t)ar * HD + kh * 32 + fko);
      float4 f0 = p[0], f1 = p[1];
      f0.x *= 0.125f; f0.y *= 0.125f; f0.z *= 0.125f; f0.w *= 0.125f;
      f1.x *= 0.125f; f1.y *= 0.125f; f1.z *= 0.125f; f1.w *= 0.125f;
      HL8 r = split8t(f0, f1);
      agh[kh][j] = asbf(r.h); agl[kh][j] = asbf(r.l);
    }
  }

  // ---- A-frags from q rows (token = i*16+fr), split in-register ----
  bf16x8 qh_[2][2], ql_[2][2];   // [i][khalf]
#pragma unroll
  for (int i = 0; i < 2; ++i)
#pragma unroll
    for (int kh = 0; kh < 2; ++kh) {
      const float4* p = (const float4*)(q + (qrow0 + i * 16 + fr) * INNER + h * 64 + kh * 32 + fko);
      HL8 r = split8t(p[0], p[1]);
      qh_[i][kh] = asbf(r.h); ql_[i][kh] = asbf(r.l);
    }

  // ---- scores (3-pass) ----
  f32x4 sa[2][4] = {};
#pragma unroll
  for (int i = 0; i < 2; ++i)
#pragma unroll
    for (int j = 0; j < 4; ++j)
#pragma unroll
      for (int kh = 0; kh < 2; ++kh) {
        sa[i][j] = __builtin_amdgcn_mfma_f32_16x16x32_bf16(qh_[i][kh], agh[kh][j], sa[i][j], 0, 0, 0);
        sa[i][j] = __builtin_amdgcn_mfma_f32_16x16x32_bf16(qh_[i][kh], agl[kh][j], sa[i][j], 0, 0, 0);
        sa[i][j] = __builtin_amdgcn_mfma_f32_16x16x32_bf16(ql_[i][kh], agh[kh][j], sa[i][j], 0, 0, 0);
      }

  // ---- + ab, wave softmax per row (rows live in 16-lane groups) ----
  float ev[2][4][4];     // [i][j][reg]
  float lsum[2][4];      // [i][reg]
#pragma unroll
  for (int i = 0; i < 2; ++i) {
#pragma unroll
    for (int r = 0; r < 4; ++r) {
      int t = gtok0 + i * 16 + 4 * rg + r;
      const float* abp = ab + ((size_t)h * NTOK + t) * AG;
      float sv[4];
      float m = -3.4e38f;
#pragma unroll
      for (int j = 0; j < 4; ++j) {
        int a = j * 16 + fr;
        int ac = a < AG ? a : AG - 1;
        float xv = sa[i][j][r] + abp[ac];
        sv[j] = (a < AG) ? xv : -3.4e38f;
        m = fmaxf(m, sv[j]);
      }
      m = fmaxf(m, __shfl_xor(m, 1, 64));
      m = fmaxf(m, __shfl_xor(m, 2, 64));
      m = fmaxf(m, __shfl_xor(m, 4, 64));
      m = fmaxf(m, __shfl_xor(m, 8, 64));
      float l = 0.f;
#pragma unroll
      for (int j = 0; j < 4; ++j) {
        int a = j * 16 + fr;
        float e = (a < AG) ? __expf(sv[j] - m) : 0.f;
        ev[i][j][r] = e;
        l += e;
      }
      l += __shfl_xor(l, 1, 64);
      l += __shfl_xor(l, 2, 64);
      l += __shfl_xor(l, 4, 64);
      l += __shfl_xor(l, 8, 64);
      lsum[i][r] = l;
    }
  }

  // ---- store P (unnormalized e) to LDS as trunc-split bf16 hi/lo ----
#pragma unroll
  for (int i = 0; i < 2; ++i)
#pragma unroll
    for (int r = 0; r < 4; ++r) {
      int lt = woff + i * 16 + 4 * rg + r;
#pragma unroll
      for (int j = 0; j < 4; ++j) {
        int a = j * 16 + fr;
        float e = ev[i][j][r];
        uint32_t u = __float_as_uint(e);
        float res = e - __uint_as_float(u & 0xFFFF0000u);
        Phi[lt * PSTR + a] = (short)(u >> 16);
        Plo[lt * PSTR + a] = (short)(__float_as_uint(res) >> 16);
      }
    }
  __syncthreads();

  // ---- PV (3-pass): A = P rows from LDS, B = avT rows (d) ----
  const short* avhp = avThi + (size_t)bh * 4096;
  const short* avlp = avTlo + (size_t)bh * 4096;
  bf16x8 vh_[2][4], vl_[2][4];   // [khalf][j]
#pragma unroll
  for (int j = 0; j < 4; ++j)
#pragma unroll
    for (int kh = 0; kh < 2; ++kh) {
      size_t o = (size_t)(j * 16 + fr) * 64 + kh * 32 + fko;
      vh_[kh][j] = asbf(*(const short8*)(avhp + o));
      vl_[kh][j] = asbf(*(const short8*)(avlp + o));
    }
  bf16x8 ph_[2][2], pl_[2][2];   // [i][khalf]
#pragma unroll
  for (int i = 0; i < 2; ++i)
#pragma unroll
    for (int kh = 0; kh < 2; ++kh) {
      int lt = woff + i * 16 + fr;
      ph_[i][kh] = asbf(*(const short8*)&Phi[lt * PSTR + kh * 32 + fko]);
      pl_[i][kh] = asbf(*(const short8*)&Plo[lt * PSTR + kh * 32 + fko]);
    }
  f32x4 oa[2][4] = {};
#pragma unroll
  for (int i = 0; i < 2; ++i)
#pragma unroll
    for (int j = 0; j < 4; ++j)
#pragma unroll
      for (int kh = 0; kh < 2; ++kh) {
        oa[i][j] = __builtin_amdgcn_mfma_f32_16x16x32_bf16(ph_[i][kh], vh_[kh][j], oa[i][j], 0, 0, 0);
        oa[i][j] = __builtin_amdgcn_mfma_f32_16x16x32_bf16(ph_[i][kh], vl_[kh][j], oa[i][j], 0, 0, 0);
        oa[i][j] = __builtin_amdgcn_mfma_f32_16x16x32_bf16(pl_[i][kh], vh_[kh][j], oa[i][j], 0, 0, 0);
      }

  // ---- normalize + write back into q (out_pre) ----
#pragma unroll
  for (int i = 0; i < 2; ++i)
#pragma unroll
    for (int r = 0; r < 4; ++r) {
      float inv = 1.f / lsum[i][r];
      float* qp = q + (qrow0 + i * 16 + 4 * rg + r) * INNER + h * 64;
#pragma unroll
      for (int j = 0; j < 4; ++j)
        qp[j * 16 + fr] = oa[i][j][r] * inv;
    }
}

// ---------------- depthwise 3x3 conv on v (de-interleaved), added into out_pre ----------------
__global__ __launch_bounds__(256) void dwc4_kernel(const float* __restrict__ v_g,
                                                   const float* __restrict__ dwc_w,
                                                   const float* __restrict__ dwc_b,
                                                   float* __restrict__ outp) {
  int idx = blockIdx.x * 256 + threadIdx.x;    // 16*4096*128 threads
  int cq = (idx & 127) << 2;
  int r  = idx >> 7;
  int x = r & 63, y = (r >> 6) & 63, b = r >> 12;
  float wreg[36];
  {
    const float4* wp = (const float4*)(dwc_w + (size_t)cq * 9);
#pragma unroll
    for (int j = 0; j < 9; ++j) {
      float4 t = wp[j];
      wreg[4 * j + 0] = t.x; wreg[4 * j + 1] = t.y;
      wreg[4 * j + 2] = t.z; wreg[4 * j + 3] = t.w;
    }
  }
  float4 s = *(const float4*)(dwc_b + cq);
  const float* vb = v_g + (size_t)b * NTOK * 512 + cq;
#pragma unroll
  for (int ky = 0; ky < 3; ++ky) {
    int yy = y + ky - 1;
    if (yy < 0 || yy > 63) continue;
#pragma unroll
    for (int kx = 0; kx < 3; ++kx) {
      int xx = x + kx - 1;
      if (xx < 0 || xx > 63) continue;
      float4 v4 = *(const float4*)(vb + (size_t)(yy * 64 + xx) * 512);
      const int t = ky * 3 + kx;
      s.x = fmaf(wreg[0 * 9 + t], v4.x, s.x);
      s.y = fmaf(wreg[1 * 9 + t], v4.y, s.y);
      s.z = fmaf(wreg[2 * 9 + t], v4.z, s.z);
      s.w = fmaf(wreg[3 * 9 + t], v4.w, s.w);
    }
  }
  size_t o = (size_t)r * INNER + cq;
  float4 cur = *(const float4*)(outp + o);
  cur.x += s.x; cur.y += s.y; cur.z += s.z; cur.w += s.w;
  *(float4*)(outp + o) = cur;
}

// ---------------- host launcher ----------------
extern "C" void kernel_launch(void* const* d_in, const int* in_sizes, int n_in,
                              void* d_out, int out_size, void* d_ws, size_t ws_size,
                              hipStream_t stream) {
  const float* x       = (const float*)d_in[0];
  const float* context = (const float*)d_in[1];
  const float* q_w     = (const float*)d_in[2];
  const float* kv_w    = (const float*)d_in[3];
  const float* proj_w  = (const float*)d_in[4];
  const float* proj_b  = (const float*)d_in[5];
  const float* conv_w  = (const float*)d_in[6];
  const float* conv_b  = (const float*)d_in[7];
  const float* dwc_w   = (const float*)d_in[8];
  const float* dwc_b   = (const float*)d_in[9];
  const float* an_bias = (const float*)d_in[10];
  const float* na_bias = (const float*)d_in[11];
  const float* ah_bias = (const float*)d_in[12];
  const float* aw_bias = (const float*)d_in[13];
  const float* ha_bias = (const float*)d_in[14];
  const float* wa_bias = (const float*)d_in[15];
  float* out = (float*)d_out;
  float* wsf = (float*)d_ws;

  float* q_buf  = wsf + Q_OFF;    // later becomes out_pre
  float* k_buf  = wsf + KV_OFF;                              // de-interleaved k: 512-float rows
  float* v_buf  = wsf + KV_OFF + (size_t)BB * NTOK * INNER;  // de-interleaved v
  float* A2     = wsf + A2_OFF;
  float* Col    = wsf + COL_OFF;
  float* Cg     = wsf + CG_OFF;
  float* agent  = wsf + AGT_OFF;
  float* pb     = wsf + PB_OFF;
  float* ab     = wsf + AB_OFF;
  float* pnum   = wsf + PNUM_OFF;  // overlays Col (retired by then)
  float* pl     = wsf + PL_OFF;
  short* avThi  = (short*)(wsf + AVT_OFF);
  short* avTlo  = avThi + (size_t)128 * 64 * 64;
  short* whi    = (short*)(wsf + WSP_OFF);      // rows 0..511 q_w, 512..1535 kv_w, 1536..2047 proj_w
  short* wlo    = whi + (size_t)2048 * 512;
  float* S1q    = wsf + COL_OFF;   // pool scratch (COL region, free until im2col)
  float* S1c    = wsf + CG_OFF;    // pool scratch (CG.. regions, free until conv)

  const int M = BB * NTOK;   // 65536

  // 0. one-time weight splits (fp32 -> bf16 hi/lo)
  split_w_kernel<<<(512 * 512 / 8 + 255) / 256, 256, 0, stream>>>(q_w, whi, wlo, 512 * 512 / 8);
  split_w_kernel<<<(1024 * 512 / 8 + 255) / 256, 256, 0, stream>>>(kv_w, whi + (size_t)512 * 512, wlo + (size_t)512 * 512, 1024 * 512 / 8);
  split_w_kernel<<<(512 * 512 / 8 + 255) / 256, 256, 0, stream>>>(proj_w, whi + (size_t)1536 * 512, wlo + (size_t)1536 * 512, 512 * 512 / 8);

  // 1. fused [q|k|v] = x @ [q_w|kv_w]^T  (MFMA split-bf16, pre-split B, XCD swizzle; 3-way epilogue)
  gemm_ws3<false><<<dim3(1536 / 128, M / 128), 256, 0, stream>>>(x, whi, wlo, nullptr,
                                                                 q_buf, k_buf, v_buf, M, DIMC);
  // 3. separable pooled concat
  pool_h_kernel<<<(BB * 7 * 64 * 768) / 256, 256, 0, stream>>>(q_buf, context, S1q, S1c);
  pool_w_kernel<<<(BB * AG * 768 + 255) / 256, 256, 0, stream>>>(S1q, S1c, A2);
  // 4. im2col
  im2col_kernel<<<(784 * 6912 + 255) / 256, 256, 0, stream>>>(A2, Col);
  // 5. conv as GEMM, split-K with atomics (zero Cg first)
  zero_kernel<<<(784 * INNER + 255) / 256, 256, 0, stream>>>(Cg, 784 * INNER);
  conv_gemm_splitk<<<dim3(INNER / 64, (784 + 63) / 64, CKS), 256, 0, stream>>>(Col, conv_w, Cg);
  // 6. scramble + conv bias -> agent[b,h,a,d]
  agent_scatter_kernel<<<(BB * HEADS * AG * HD + 255) / 256, 256, 0, stream>>>(Cg, conv_b, agent);
  // 7./8. bias tables
  pb_kernel<<<(HEADS * AG * NTOK + 255) / 256, 256, 0, stream>>>(an_bias, ah_bias, aw_bias, pb);
  ab_kernel<<<(HEADS * NTOK * AG + 255) / 256, 256, 0, stream>>>(na_bias, ha_bias, wa_bias, ab);
  // 9. agent attention via MFMA -> partials -> avT (transposed, bf16-split agent_v)
  agent_attn_mfma<<<dim3(ASPLIT, HEADS, BB), 256, 0, stream>>>(k_buf, v_buf, agent, pb, pnum, pl);
  agent_attn_combine<<<(128 * 64 * 64) / 256, 256, 0, stream>>>(pnum, pl, avThi, avTlo);
  // 10. q attention via MFMA (q_buf overwritten with out_pre)
  q_attn_mfma<<<dim3(NTOK / 128, HEADS, BB), 256, 0, stream>>>(agent, avThi, avTlo, ab, q_buf);
  // 11. depthwise conv on v added into out_pre (vectorized: 4 ch/thread, dense v rows)
  dwc4_kernel<<<(BB * NTOK * 128) / 256, 256, 0, stream>>>(v_buf, dwc_w, dwc_b, q_buf);
  // 12. final projection with bias (MFMA, XCD swizzle)
  gemm_ws3<true><<<dim3(DIMC / 128, M / 128), 256, 0, stream>>>(q_buf, whi + (size_t)1536 * 512, wlo + (size_t)1536 * 512,
                                                                proj_b, out, out, out, M, INNER);

  (void)in_sizes; (void)n_in; (void)out_size; (void)ws_size;
}

// Round 12
// 1347.519 us; speedup vs baseline: 1.0434x; 1.0391x over previous
//
#include <hip/hip_runtime.h>
#include <cstdint>
#include <cstddef>

// Problem constants (fixed by setup_inputs)
#define BB    16
#define NTOK  4096
#define DIMC  512
#define INNER 512
#define CTXC  256
#define HEADS 8
#define HD    64
#define AG    49
#define ASPLIT 8   // n-splits for agent attention
#define CONVK 6912
#define CKS   16   // k-splits for conv GEMM (chunk = 432 = 27*16)

// ---------------- workspace layout (floats) ----------------
static const size_t Q_OFF   = 0;                                     // q / out_pre: 16*4096*512
static const size_t KV_OFF  = Q_OFF  + (size_t)BB*NTOK*INNER;        // k_buf: 16*4096*512, then v_buf: 16*4096*512
static const size_t A2_OFF  = KV_OFF + (size_t)BB*NTOK*2*INNER;      // pooled concat: 16*49*768
static const size_t COL_OFF = A2_OFF + (size_t)BB*AG*768;            // im2col: 784*6912 (pool S1q scratch before; attn partials + avT after)
static const size_t CG_OFF  = COL_OFF+ (size_t)BB*AG*768*9;          // conv gemm out: 784*512 (pool S1c scratch)
static const size_t AGT_OFF = CG_OFF + (size_t)BB*AG*INNER;          // agent[b,h,a,d]
static const size_t AGV_OFF = AGT_OFF+ (size_t)BB*HEADS*AG*HD;       // (retired)
static const size_t PB_OFF  = AGV_OFF+ (size_t)BB*HEADS*AG*HD;       // pb[h,a,n]
static const size_t AB_OFF  = PB_OFF + (size_t)HEADS*AG*NTOK;        // ab[h,n,a]
static const size_t WSP_OFF = AB_OFF + (size_t)HEADS*NTOK*AG;        // pre-split weights: 2*2048*512 shorts = 1,048,576 floats
// overlays of the retired COL region:
static const size_t PNUM_OFF = COL_OFF;                              // 8*128*64*64 = 4,194,304 floats
static const size_t PL_OFF   = PNUM_OFF + (size_t)ASPLIT*128*64*64;  // 8*128*64    = 65,536 floats
static const size_t AVT_OFF  = PL_OFF + (size_t)ASPLIT*128*64;       // avT hi/lo: 2*128*64*64 shorts = 524,288 floats
// (4,259,840 + 524,288 = 4,784,128 < COL region's 5,419,008 floats)

typedef __attribute__((ext_vector_type(8))) short  short8;   // 8 bf16 bit-patterns (4 VGPRs)
typedef __attribute__((ext_vector_type(8))) __bf16 bf16x8;   // canonical MFMA operand type
typedef __attribute__((ext_vector_type(4))) float  f32x4;    // MFMA accumulator

union SB8 { short8 s; bf16x8 b; };

__device__ inline bf16x8 asbf(short8 v) { SB8 u; u.s = v; return u.b; }

// round-to-nearest-even fp32 -> bf16 bits
__device__ inline unsigned short bfrn(float x) {
  uint32_t u = __float_as_uint(x);
  return (unsigned short)((u + 0x7FFFu + ((u >> 16) & 1u)) >> 16);
}

struct HL8 { short8 h, l; };

// split 8 fp32 into bf16 hi (RNE) + bf16 lo (RNE) — used once for weights
__device__ inline HL8 split8(float4 f0, float4 f1) {
  HL8 r;
  float v0[4] = {f0.x, f0.y, f0.z, f0.w};
  float v1[4] = {f1.x, f1.y, f1.z, f1.w};
#pragma unroll
  for (int j = 0; j < 4; ++j) {
    unsigned short hb = bfrn(v0[j]);
    r.h[j] = (short)hb;
    r.l[j] = (short)bfrn(v0[j] - __uint_as_float((uint32_t)hb << 16));
  }
#pragma unroll
  for (int j = 0; j < 4; ++j) {
    unsigned short hb = bfrn(v1[j]);
    r.h[j + 4] = (short)hb;
    r.l[j + 4] = (short)bfrn(v1[j] - __uint_as_float((uint32_t)hb << 16));
  }
  return r;
}

// RNE-hi + TRUNC-lo split — the R9 GEMM config (compiles to 84 VGPR / 6 waves/SIMD).
// R10's trunc-trunc variant raised peak register pressure past the 84 boundary (88-104 VGPR,
// occupancy 32%->22%) and cost +64us; attribution: staging value-lifetime change, not epilogue.
__device__ inline HL8 split8r(float4 f0, float4 f1) {
  HL8 r;
  float v[8] = {f0.x, f0.y, f0.z, f0.w, f1.x, f1.y, f1.z, f1.w};
#pragma unroll
  for (int j = 0; j < 8; ++j) {
    uint32_t u = __float_as_uint(v[j]);
    uint32_t hb = (u + 0x7FFFu + ((u >> 16) & 1u)) >> 16;
    r.h[j] = (short)hb;
    float res = v[j] - __uint_as_float(hb << 16);
    r.l[j] = (short)(__float_as_uint(res) >> 16);
  }
  return r;
}

// TRUNC-TRUNC split (fewest VALU ops) — used in attention kernels only
__device__ inline HL8 split8t(float4 f0, float4 f1) {
  HL8 r;
  float v[8] = {f0.x, f0.y, f0.z, f0.w, f1.x, f1.y, f1.z, f1.w};
#pragma unroll
  for (int j = 0; j < 8; ++j) {
    uint32_t u = __float_as_uint(v[j]);
    r.h[j] = (short)(u >> 16);
    float res = v[j] - __uint_as_float(u & 0xFFFF0000u);
    r.l[j] = (short)(__float_as_uint(res) >> 16);
  }
  return r;
}

// ---------------- one-time weight split: fp32 -> bf16 hi/lo ----------------
__global__ void split_w_kernel(const float* __restrict__ src, short* __restrict__ dhi,
                               short* __restrict__ dlo, int n8) {
  int i = blockIdx.x * 256 + threadIdx.x;
  if (i >= n8) return;
  const float4* s = (const float4*)src + (size_t)i * 2;
  HL8 r = split8(s[0], s[1]);
  *(short8*)(dhi + (size_t)i * 8) = r.h;
  *(short8*)(dlo + (size_t)i * 8) = r.l;
}

// ---------------- MFMA split-bf16 GEMM, 128x128 tile: [C1|C2|C3] = A(MxK) * Bw^T (+bias) ----------------
// 3-pass hi/lo split: C = Ah*Bh + Ah*Bl + Al*Bh. B pre-split bf16.
// XCD-aware block swizzle (nwg % 8 == 0). Output col-tile t = bnT>>9 routes to C1/C2/C3 (each 512 wide).
// LDS row stride 40; R9 split (split8r); plain launch_bounds (R11 lesson: min-waves request
// is abandoned by the allocator when unmeetable -> 104 VGPR; do not use).
#define LSTR 40
template <bool ADD_BIAS>
__global__ __launch_bounds__(256) void gemm_ws3(const float* __restrict__ A,
                                                const short* __restrict__ Bhi_g,
                                                const short* __restrict__ Blo_g,
                                                const float* __restrict__ bias,
                                                float* __restrict__ C1,
                                                float* __restrict__ C2,
                                                float* __restrict__ C3,
                                                int M, int K) {
  __shared__ short Ahi[128 * LSTR];
  __shared__ short Alo[128 * LSTR];
  __shared__ short Bhi[128 * LSTR];
  __shared__ short Blo[128 * LSTR];
  const int tid  = threadIdx.x;
  const int lane = tid & 63;
  const int wave = tid >> 6;
  const int wm = wave >> 1, wn = wave & 1;          // 2x2 wave grid
  // XCD-aware swizzle: consecutive blocks within an XCD share an A m-panel
  const int nwg = gridDim.x * gridDim.y;
  const int lin = blockIdx.y * gridDim.x + blockIdx.x;
  const int swz = (lin & 7) * (nwg >> 3) + (lin >> 3);
  const int bx = swz % gridDim.x, by = swz / gridDim.x;
  const int bm = by * 128, bnT = bx * 128;
  // staging role: 2 threads per row, 16 consecutive k each
  const int srow  = tid >> 1;
  const int shalf = (tid & 1) << 4;                 // 0 or 16 (elements)
  // fragment role
  const int fr  = lane & 15;                        // row/col within 16x16 frag
  const int fko = (lane >> 4) << 3;                 // k offset: 0,8,16,24

  f32x4 acc[4][4] = {};

  for (int k0 = 0; k0 < K; k0 += 32) {
    {
      // A: fp32 load + in-kernel split (R9 config)
      const float4* ap = (const float4*)(A + (size_t)(bm + srow) * K + k0 + shalf);
      float4 a0 = ap[0], a1 = ap[1], a2 = ap[2], a3 = ap[3];
      HL8 r0 = split8r(a0, a1);
      *(short8*)&Ahi[srow * LSTR + shalf] = r0.h;
      *(short8*)&Alo[srow * LSTR + shalf] = r0.l;
      HL8 r1 = split8r(a2, a3);
      *(short8*)&Ahi[srow * LSTR + shalf + 8] = r1.h;
      *(short8*)&Alo[srow * LSTR + shalf + 8] = r1.l;
      // B: pre-split bf16, straight copy to LDS
      const short* bhp = Bhi_g + (size_t)(bnT + srow) * K + k0 + shalf;
      *(short8*)&Bhi[srow * LSTR + shalf]     = *(const short8*)bhp;
      *(short8*)&Bhi[srow * LSTR + shalf + 8] = *(const short8*)(bhp + 8);
      const short* blp = Blo_g + (size_t)(bnT + srow) * K + k0 + shalf;
      *(short8*)&Blo[srow * LSTR + shalf]     = *(const short8*)blp;
      *(short8*)&Blo[srow * LSTR + shalf + 8] = *(const short8*)(blp + 8);
    }
    __syncthreads();
    bf16x8 ah[4], al[4], bh[4], bl[4];
#pragma unroll
    for (int i = 0; i < 4; ++i) {
      int ra = wm * 64 + i * 16 + fr;
      ah[i] = asbf(*(const short8*)&Ahi[ra * LSTR + fko]);
      al[i] = asbf(*(const short8*)&Alo[ra * LSTR + fko]);
      int rb = wn * 64 + i * 16 + fr;
      bh[i] = asbf(*(const short8*)&Bhi[rb * LSTR + fko]);
      bl[i] = asbf(*(const short8*)&Blo[rb * LSTR + fko]);
    }
#pragma unroll
    for (int i = 0; i < 4; ++i)
#pragma unroll
      for (int j = 0; j < 4; ++j) {
        acc[i][j] = __builtin_amdgcn_mfma_f32_16x16x32_bf16(ah[i], bh[j], acc[i][j], 0, 0, 0);
        acc[i][j] = __builtin_amdgcn_mfma_f32_16x16x32_bf16(ah[i], bl[j], acc[i][j], 0, 0, 0);
        acc[i][j] = __builtin_amdgcn_mfma_f32_16x16x32_bf16(al[i], bh[j], acc[i][j], 0, 0, 0);
      }
    __syncthreads();
  }

  // epilogue: C/D layout col=lane&15, row=4*(lane>>4)+reg; route to C1/C2/C3 (512 cols each)
  const int crow0 = wm * 64 + ((lane >> 4) << 2);
  const int ccol0 = wn * 64 + fr;
  const int t = bnT >> 9;
  float* Cb = (t == 0) ? C1 : (t == 1) ? C2 : C3;
  const int coff = bnT & 511;
  float bs[4];
  if (ADD_BIAS) {
#pragma unroll
    for (int j = 0; j < 4; ++j) bs[j] = bias[bnT + ccol0 + j * 16];
  }
#pragma unroll
  for (int i = 0; i < 4; ++i) {
#pragma unroll
    for (int r = 0; r < 4; ++r) {
      size_t row = (size_t)(bm + crow0 + i * 16 + r);
      float* cp = Cb + row * 512 + coff + ccol0;
#pragma unroll
      for (int j = 0; j < 4; ++j) {
        float v = acc[i][j][r];
        if (ADD_BIAS) v += bs[j];
        cp[j * 16] = v;
      }
    }
  }
}

// ---------------- zero-fill (graph-capture-safe memset) ----------------
__global__ void zero_kernel(float* __restrict__ p, int n) {
  int i = blockIdx.x * 256 + threadIdx.x;
  if (i < n) p[i] = 0.f;
}

// ---------------- conv GEMM, split-K + atomics: Cg[784][512] += Col[784][6912] @ W[512][6912]^T ----------------
__global__ __launch_bounds__(256) void conv_gemm_splitk(const float* __restrict__ A,
                                                        const float* __restrict__ Bw,
                                                        float* __restrict__ C) {
  __shared__ float As[16][72];
  __shared__ float Bs[16][72];
  const int tid = threadIdx.x;
  const int tx = tid & 15, ty = tid >> 4;
  const int bn = blockIdx.x * 64;
  const int bm = blockIdx.y * 64;
  const int k_begin = blockIdx.z * (CONVK / CKS);
  const int k_end = k_begin + (CONVK / CKS);
  const int row = tid >> 2, c4 = (tid & 3) << 2;
  float acc[4][4] = {};
  for (int k0 = k_begin; k0 < k_end; k0 += 16) {
    {
      int m = bm + row;
      float4 av = {0.f, 0.f, 0.f, 0.f};
      if (m < 784) av = *(const float4*)(A + (size_t)m * CONVK + k0 + c4);
      As[c4 + 0][row] = av.x; As[c4 + 1][row] = av.y;
      As[c4 + 2][row] = av.z; As[c4 + 3][row] = av.w;
      float4 bv = *(const float4*)(Bw + (size_t)(bn + row) * CONVK + k0 + c4);
      Bs[c4 + 0][row] = bv.x; Bs[c4 + 1][row] = bv.y;
      Bs[c4 + 2][row] = bv.z; Bs[c4 + 3][row] = bv.w;
    }
    __syncthreads();
#pragma unroll
    for (int k = 0; k < 16; ++k) {
      float a[4], b[4];
#pragma unroll
      for (int i = 0; i < 4; ++i) a[i] = As[k][ty * 4 + i];
#pragma unroll
      for (int j = 0; j < 4; ++j) b[j] = Bs[k][tx * 4 + j];
#pragma unroll
      for (int i = 0; i < 4; ++i)
#pragma unroll
        for (int j = 0; j < 4; ++j) acc[i][j] = fmaf(a[i], b[j], acc[i][j]);
    }
    __syncthreads();
  }
#pragma unroll
  for (int i = 0; i < 4; ++i) {
    int m = bm + ty * 4 + i;
    if (m >= 784) continue;
#pragma unroll
    for (int j = 0; j < 4; ++j)
      atomicAdd(C + (size_t)m * INNER + bn + tx * 4 + j, acc[i][j]);
  }
}

// ---------------- separable overlapping avg-pool, stage 1: pool over h ----------------
__global__ void pool_h_kernel(const float* __restrict__ q, const float* __restrict__ ctx,
                              float* __restrict__ S1q, float* __restrict__ S1c) {
  int idx = blockIdx.x * 256 + threadIdx.x;    // 16*7*64*768
  if (idx >= BB * 7 * 64 * 768) return;
  int c  = idx % 768;
  int w  = (idx / 768) & 63;
  int ph = (idx / (768 * 64)) % 7;
  int b  = idx / (768 * 64 * 7);
  int hs = ph * 64 / 7, he = ((ph + 1) * 64 + 6) / 7;
  float s = 0.f;
  if (c < 512) {
    const float* p = q + ((size_t)b * NTOK + hs * 64 + w) * INNER + c;
    for (int h = hs; h < he; ++h) { s += *p; p += 64 * INNER; }
    S1q[((size_t)(b * 7 + ph) * 64 + w) * 512 + c] = s;
  } else {
    int cc = c - 512;
    const float* p = ctx + ((size_t)b * NTOK + hs * 64 + w) * CTXC + cc;
    for (int h = hs; h < he; ++h) { s += *p; p += 64 * CTXC; }
    S1c[((size_t)(b * 7 + ph) * 64 + w) * 256 + cc] = s;
  }
}

// ---------------- pool stage 2: pool over w, normalize -> A2[b,49,768] ----------------
__global__ void pool_w_kernel(const float* __restrict__ S1q, const float* __restrict__ S1c,
                              float* __restrict__ A2) {
  int idx = blockIdx.x * 256 + threadIdx.x;    // 16*49*768
  if (idx >= BB * AG * 768) return;
  int c = idx % 768;
  int p = (idx / 768) % AG;
  int b = idx / (768 * AG);
  int i = p / 7, j = p % 7;
  int hs = i * 64 / 7, he = ((i + 1) * 64 + 6) / 7;
  int ws = j * 64 / 7, we = ((j + 1) * 64 + 6) / 7;
  float inv = 1.f / (float)((he - hs) * (we - ws));
  float s = 0.f;
  if (c < 512) {
    const float* pp = S1q + ((size_t)(b * 7 + i) * 64 + ws) * 512 + c;
    for (int w = ws; w < we; ++w) { s += *pp; pp += 512; }
  } else {
    const float* pp = S1c + ((size_t)(b * 7 + i) * 64 + ws) * 256 + (c - 512);
    for (int w = ws; w < we; ++w) { s += *pp; pp += 256; }
  }
  A2[((size_t)b * AG + p) * 768 + c] = s * inv;
}

// ---------------- im2col of scrambled agent_in: Col[b*49+p][ic*9+ky*3+kx] ----------------
__global__ void im2col_kernel(const float* __restrict__ A2, float* __restrict__ Col) {
  int idx = blockIdx.x * 256 + threadIdx.x;    // 784*6912
  if (idx >= 784 * 6912) return;
  int r = idx / 6912, t = idx % 6912;
  int ic = t / 9, ky = (t % 9) / 3, kx = t % 3;
  int b = r / AG, p = r % AG;
  int y = p / 7 + ky - 1, x = p % 7 + kx - 1;
  float v = 0.f;
  if (y >= 0 && y < 7 && x >= 0 && x < 7) {
    int g = ic * 49 + y * 7 + x;
    v = A2[((size_t)b * AG + g / 768) * 768 + (g % 768)];
  }
  Col[(size_t)idx] = v;
}

// ---------------- scramble conv output -> agent[b,h,a,d] (+conv bias) ----------------
__global__ void agent_scatter_kernel(const float* __restrict__ Cg, const float* __restrict__ conv_b,
                                     float* __restrict__ agent) {
  int idx = blockIdx.x * 256 + threadIdx.x;   // 16*8*49*64
  if (idx >= BB * HEADS * AG * HD) return;
  int d = idx & 63;
  int a = (idx >> 6) % AG;
  int h = (idx / (64 * AG)) % HEADS;
  int b = idx / (64 * AG * HEADS);
  int f = a * 512 + h * 64 + d;
  int oc = f / 49, p = f % 49;
  agent[idx] = Cg[((size_t)b * AG + p) * INNER + oc] + conv_b[oc];
}

// ---------------- jax bilinear resize 7->64 (half-pixel, renorm == clamp) ----------------
__device__ inline float bilinear7(const float* __restrict__ Bm, int y, int x) {
  float fy = (y + 0.5f) * (7.f / 64.f) - 0.5f;
  float fx = (x + 0.5f) * (7.f / 64.f) - 0.5f;
  fy = fminf(fmaxf(fy, 0.f), 6.f);
  fx = fminf(fmaxf(fx, 0.f), 6.f);
  int y0 = min((int)floorf(fy), 5);
  int x0 = min((int)floorf(fx), 5);
  float ty = fy - y0, tx = fx - x0;
  float v00 = Bm[y0 * 7 + x0],     v01 = Bm[y0 * 7 + x0 + 1];
  float v10 = Bm[(y0 + 1) * 7 + x0], v11 = Bm[(y0 + 1) * 7 + x0 + 1];
  return (1.f - ty) * ((1.f - tx) * v00 + tx * v01) + ty * ((1.f - tx) * v10 + tx * v11);
}

// pb[h][a][n] = resize(an_bias[h,a])(y,x) + ah[h,a,y] + aw[h,a,x]
__global__ void pb_kernel(const float* __restrict__ an_bias, const float* __restrict__ ah,
                          const float* __restrict__ aw, float* __restrict__ pb) {
  int idx = blockIdx.x * 256 + threadIdx.x;   // 8*49*4096
  if (idx >= HEADS * AG * NTOK) return;
  int nn = idx & (NTOK - 1);
  int a = (idx / NTOK) % AG;
  int h = idx / (NTOK * AG);
  int y = nn >> 6, x = nn & 63;
  float v = bilinear7(an_bias + ((size_t)h * AG + a) * 49, y, x);
  v += ah[((size_t)h * AG + a) * 64 + y] + aw[((size_t)h * AG + a) * 64 + x];
  pb[idx] = v;
}

// ab[h][n][a] = resize(na_bias[h,a])(y,x) + ha[h,y,a] + wa[h,x,a]
__global__ void ab_kernel(const float* __restrict__ na_bias, const float* __restrict__ ha,
                          const float* __restrict__ wa, float* __restrict__ ab) {
  int idx = blockIdx.x * 256 + threadIdx.x;   // 8*4096*49
  if (idx >= HEADS * NTOK * AG) return;
  int a = idx % AG;
  int nn = (idx / AG) & (NTOK - 1);
  int h = idx / (AG * NTOK);
  int y = nn >> 6, x = nn & 63;
  float v = bilinear7(na_bias + ((size_t)h * AG + a) * 49, y, x);
  v += ha[((size_t)h * 64 + y) * AG + a] + wa[((size_t)h * 64 + x) * AG + a];
  ab[idx] = v;
}

// ---------------- agent attention via MFMA (split-bf16 3-pass QK^T and PV) ----------------
// k_buf/v_buf are de-interleaved (512-float rows).
#define ESTR 72
__global__ __launch_bounds__(256, 2) void agent_attn_mfma(const float* __restrict__ k_g,
                                                          const float* __restrict__ v_g,
                                                          const float* __restrict__ agent,
                                                          const float* __restrict__ pb,
                                                          float* __restrict__ part_num,
                                                          float* __restrict__ part_l) {
  const int split = blockIdx.x;                 // 0..ASPLIT-1
  const int h = blockIdx.y, b = blockIdx.z;
  const int bh = b * HEADS + h;
  __shared__ short eThi[64 * ESTR];
  __shared__ short eTlo[64 * ESTR];
  __shared__ short vThi[64 * ESTR];
  __shared__ short vTlo[64 * ESTR];
  __shared__ float lred[4][64];
  const int tid = threadIdx.x;
  const int lane = tid & 63;
  const int w = tid >> 6;                       // wave id
  const int fr = lane & 15;
  const int fko = (lane >> 4) << 3;             // 0,8,16,24
  const int rg = lane >> 4;                     // C-layout row group

  // ---- persistent A-frags: agent rows a=i*16+fr (clamped; masked later), scaled 0.125, split ----
  bf16x8 agh[4][2], agl[4][2];
#pragma unroll
  for (int i = 0; i < 4; ++i) {
    int ar = i * 16 + fr; if (ar > AG - 1) ar = AG - 1;
#pragma unroll
    for (int kh = 0; kh < 2; ++kh) {
      const float4* p = (const float4*)(agent + ((size_t)bh * AG + ar) * HD + kh * 32 + fko);
      float4 f0 = p[0], f1 = p[1];
      f0.x *= 0.125f; f0.y *= 0.125f; f0.z *= 0.125f; f0.w *= 0.125f;
      f1.x *= 0.125f; f1.y *= 0.125f; f1.z *= 0.125f; f1.w *= 0.125f;
      HL8 r = split8t(f0, f1);
      agh[i][kh] = asbf(r.h); agl[i][kh] = asbf(r.l);
    }
  }

  float lacc[4][4] = {};       // [i][reg] per-lane l partials (this lane's n column)
  f32x4 oa[4] = {};            // PV acc: rows a=i*16+4rg+reg, col d=w*16+fr

  const float* kb = k_g + (size_t)b * NTOK * 512 + h * 64;   // k rows, stride 512
  const float* vb = v_g + (size_t)b * NTOK * 512 + h * 64;   // v rows, stride 512
  const float* pbh = pb + (size_t)h * AG * NTOK;
  const int nrow = tid & 63, dq = tid >> 6;                   // vT staging mapping

  for (int c = 0; c < 8; ++c) {
    const int n0 = split * 512 + c * 64;
    // ---- stage vT[d][n] split-bf16 ----
    {
      const float* vr = vb + (size_t)(n0 + nrow) * 512;
#pragma unroll
      for (int p = 0; p < 2; ++p) {
        int d0 = dq * 16 + p * 8;
        float4 f0 = *(const float4*)(vr + d0);
        float4 f1 = *(const float4*)(vr + d0 + 4);
        HL8 r = split8t(f0, f1);
#pragma unroll
        for (int j = 0; j < 8; ++j) {
          vThi[(d0 + j) * ESTR + nrow] = r.h[j];
          vTlo[(d0 + j) * ESTR + nrow] = r.l[j];
        }
      }
    }
    // ---- QK: B-frags from k row n = n0 + w*16 + fr ----
    bf16x8 kh_[2], kl_[2];
    {
      const float* kr = kb + (size_t)(n0 + w * 16 + fr) * 512;
#pragma unroll
      for (int kh = 0; kh < 2; ++kh) {
        float4 f0 = *(const float4*)(kr + kh * 32 + fko);
        float4 f1 = *(const float4*)(kr + kh * 32 + fko + 4);
        HL8 r = split8t(f0, f1);
        kh_[kh] = asbf(r.h); kl_[kh] = asbf(r.l);
      }
    }
    f32x4 sa[4] = {};
#pragma unroll
    for (int i = 0; i < 4; ++i)
#pragma unroll
      for (int kh = 0; kh < 2; ++kh) {
        sa[i] = __builtin_amdgcn_mfma_f32_16x16x32_bf16(agh[i][kh], kh_[kh], sa[i], 0, 0, 0);
        sa[i] = __builtin_amdgcn_mfma_f32_16x16x32_bf16(agh[i][kh], kl_[kh], sa[i], 0, 0, 0);
        sa[i] = __builtin_amdgcn_mfma_f32_16x16x32_bf16(agl[i][kh], kh_[kh], sa[i], 0, 0, 0);
      }
    // ---- e = exp(s + pb) masked; accumulate l; write trunc-split e to eT ----
    const int ncol = n0 + w * 16 + fr;
#pragma unroll
    for (int i = 0; i < 4; ++i)
#pragma unroll
      for (int r = 0; r < 4; ++r) {
        int a = i * 16 + 4 * rg + r;
        float e = 0.f;
        if (a < AG) e = __expf(sa[i][r] + pbh[(size_t)a * NTOK + ncol]);
        lacc[i][r] += e;
        uint32_t u = __float_as_uint(e);
        float res = e - __uint_as_float(u & 0xFFFF0000u);
        eThi[a * ESTR + w * 16 + fr] = (short)(u >> 16);
        eTlo[a * ESTR + w * 16 + fr] = (short)(__float_as_uint(res) >> 16);
      }
    __syncthreads();
    // ---- PV: A = eT rows, B = vT rows d = w*16+fr ----
    bf16x8 vh_[2], vl_[2];
#pragma unroll
    for (int kh = 0; kh < 2; ++kh) {
      vh_[kh] = asbf(*(const short8*)&vThi[(w * 16 + fr) * ESTR + kh * 32 + fko]);
      vl_[kh] = asbf(*(const short8*)&vTlo[(w * 16 + fr) * ESTR + kh * 32 + fko]);
    }
#pragma unroll
    for (int i = 0; i < 4; ++i)
#pragma unroll
      for (int kh = 0; kh < 2; ++kh) {
        bf16x8 eh = asbf(*(const short8*)&eThi[(i * 16 + fr) * ESTR + kh * 32 + fko]);
        bf16x8 el = asbf(*(const short8*)&eTlo[(i * 16 + fr) * ESTR + kh * 32 + fko]);
        oa[i] = __builtin_amdgcn_mfma_f32_16x16x32_bf16(eh, vh_[kh], oa[i], 0, 0, 0);
        oa[i] = __builtin_amdgcn_mfma_f32_16x16x32_bf16(eh, vl_[kh], oa[i], 0, 0, 0);
        oa[i] = __builtin_amdgcn_mfma_f32_16x16x32_bf16(el, vh_[kh], oa[i], 0, 0, 0);
      }
    __syncthreads();
  }

  // ---- l: reduce over fr (16-lane groups), then across waves via LDS ----
#pragma unroll
  for (int i = 0; i < 4; ++i)
#pragma unroll
    for (int r = 0; r < 4; ++r) {
      float l = lacc[i][r];
      l += __shfl_xor(l, 1, 64); l += __shfl_xor(l, 2, 64);
      l += __shfl_xor(l, 4, 64); l += __shfl_xor(l, 8, 64);
      lacc[i][r] = l;
    }
  if (fr == 0) {
#pragma unroll
    for (int i = 0; i < 4; ++i)
#pragma unroll
      for (int r = 0; r < 4; ++r)
        lred[w][i * 16 + 4 * rg + r] = lacc[i][r];
  }
  __syncthreads();

  float* pn = part_num + ((size_t)(split * 128 + bh)) * 64 * 64;
  float* pl = part_l + (size_t)(split * 128 + bh) * 64;
#pragma unroll
  for (int i = 0; i < 4; ++i)
#pragma unroll
    for (int r = 0; r < 4; ++r) {
      int a = i * 16 + 4 * rg + r;
      if (a < AG) pn[a * 64 + w * 16 + fr] = oa[i][r];
    }
  if (tid < AG) pl[tid] = lred[0][tid] + lred[1][tid] + lred[2][tid] + lred[3][tid];
}

// ---------------- combine partials -> transposed, split agent_v: avT[bh][d][a] bf16 hi/lo ----------------
__global__ void agent_attn_combine(const float* __restrict__ part_num,
                                   const float* __restrict__ part_l,
                                   short* __restrict__ avThi, short* __restrict__ avTlo) {
  int idx = blockIdx.x * 256 + threadIdx.x;   // 128*64*64
  if (idx >= 128 * 64 * 64) return;
  int a = idx & 63;
  int d = (idx >> 6) & 63;
  int bh = idx >> 12;
  float v = 0.f;
  if (a < AG) {
    float num = 0.f, l = 0.f;
#pragma unroll
    for (int s = 0; s < ASPLIT; ++s) {
      num += part_num[((size_t)(s * 128 + bh)) * 4096 + a * 64 + d];
      l += part_l[(size_t)(s * 128 + bh) * 64 + a];
    }
    v = num / l;
  }
  unsigned short hb = bfrn(v);
  float res = v - __uint_as_float((uint32_t)hb << 16);
  avThi[(size_t)bh * 4096 + d * 64 + a] = (short)hb;
  avTlo[(size_t)bh * 4096 + d * 64 + a] = (short)(__float_as_uint(res) >> 16);
}

// ---------------- q attention via MFMA: softmax_a(q*scale . agent^T + ab) @ agent_v ----------------
#define PSTR 80
__global__ __launch_bounds__(256) void q_attn_mfma(const float* __restrict__ agent,
                                                   const short* __restrict__ avThi,
                                                   const short* __restrict__ avTlo,
                                                   const float* __restrict__ ab,
                                                   float* __restrict__ q) {
  const int tile = blockIdx.x;   // 32 tiles of 128 tokens
  const int h = blockIdx.y, b = blockIdx.z;
  const int bh = b * HEADS + h;
  __shared__ short Phi[128 * PSTR];
  __shared__ short Plo[128 * PSTR];
  const int tid = threadIdx.x;
  const int lane = tid & 63;
  const int wave = tid >> 6;
  const int woff = wave * 32;          // token offset within tile
  const int fr = lane & 15;
  const int fko = (lane >> 4) << 3;    // 0,8,16,24
  const int rg = lane >> 4;            // C-layout row group

  const size_t agbase = (size_t)bh * AG * HD;
  const int gtok0 = tile * 128 + woff;              // token within [0,4096)
  const size_t qrow0 = (size_t)b * NTOK + gtok0;    // global q row of wave

  // ---- B-frags from agent rows (a = j*16+fr clamped), scaled 0.125, split in-register ----
  bf16x8 agh[2][4], agl[2][4];   // [khalf][j]
#pragma unroll
  for (int j = 0; j < 4; ++j) {
    int ar = j * 16 + fr; if (ar > AG - 1) ar = AG - 1;
#pragma unroll
    for (int kh = 0; kh < 2; ++kh) {
      const float4* p = (const float4*)(agent + agbase + (size_t)ar * HD + kh * 32 + fko);
      float4 f0 = p[0], f1 = p[1];
      f0.x *= 0.125f; f0.y *= 0.125f; f0.z *= 0.125f; f0.w *= 0.125f;
      f1.x *= 0.125f; f1.y *= 0.125f; f1.z *= 0.125f; f1.w *= 0.125f;
      HL8 r = split8t(f0, f1);
      agh[kh][j] = asbf(r.h); agl[kh][j] = asbf(r.l);
    }
  }

  // ---- A-frags from q rows (token = i*16+fr), split in-register ----
  bf16x8 qh_[2][2], ql_[2][2];   // [i][khalf]
#pragma unroll
  for (int i = 0; i < 2; ++i)
#pragma unroll
    for (int kh = 0; kh < 2; ++kh) {
      const float4* p = (const float4*)(q + (qrow0 + i * 16 + fr) * INNER + h * 64 + kh * 32 + fko);
      HL8 r = split8t(p[0], p[1]);
      qh_[i][kh] = asbf(r.h); ql_[i][kh] = asbf(r.l);
    }

  // ---- scores (3-pass) ----
  f32x4 sa[2][4] = {};
#pragma unroll
  for (int i = 0; i < 2; ++i)
#pragma unroll
    for (int j = 0; j < 4; ++j)
#pragma unroll
      for (int kh = 0; kh < 2; ++kh) {
        sa[i][j] = __builtin_amdgcn_mfma_f32_16x16x32_bf16(qh_[i][kh], agh[kh][j], sa[i][j], 0, 0, 0);
        sa[i][j] = __builtin_amdgcn_mfma_f32_16x16x32_bf16(qh_[i][kh], agl[kh][j], sa[i][j], 0, 0, 0);
        sa[i][j] = __builtin_amdgcn_mfma_f32_16x16x32_bf16(ql_[i][kh], agh[kh][j], sa[i][j], 0, 0, 0);
      }

  // ---- + ab, wave softmax per row (rows live in 16-lane groups) ----
  float ev[2][4][4];     // [i][j][reg]
  float lsum[2][4];      // [i][reg]
#pragma unroll
  for (int i = 0; i < 2; ++i) {
#pragma unroll
    for (int r = 0; r < 4; ++r) {
      int t = gtok0 + i * 16 + 4 * rg + r;
      const float* abp = ab + ((size_t)h * NTOK + t) * AG;
      float sv[4];
      float m = -3.4e38f;
#pragma unroll
      for (int j = 0; j < 4; ++j) {
        int a = j * 16 + fr;
        int ac = a < AG ? a : AG - 1;
        float xv = sa[i][j][r] + abp[ac];
        sv[j] = (a < AG) ? xv : -3.4e38f;
        m = fmaxf(m, sv[j]);
      }
      m = fmaxf(m, __shfl_xor(m, 1, 64));
      m = fmaxf(m, __shfl_xor(m, 2, 64));
      m = fmaxf(m, __shfl_xor(m, 4, 64));
      m = fmaxf(m, __shfl_xor(m, 8, 64));
      float l = 0.f;
#pragma unroll
      for (int j = 0; j < 4; ++j) {
        int a = j * 16 + fr;
        float e = (a < AG) ? __expf(sv[j] - m) : 0.f;
        ev[i][j][r] = e;
        l += e;
      }
      l += __shfl_xor(l, 1, 64);
      l += __shfl_xor(l, 2, 64);
      l += __shfl_xor(l, 4, 64);
      l += __shfl_xor(l, 8, 64);
      lsum[i][r] = l;
    }
  }

  // ---- store P (unnormalized e) to LDS as trunc-split bf16 hi/lo ----
#pragma unroll
  for (int i = 0; i < 2; ++i)
#pragma unroll
    for (int r = 0; r < 4; ++r) {
      int lt = woff + i * 16 + 4 * rg + r;
#pragma unroll
      for (int j = 0; j < 4; ++j) {
        int a = j * 16 + fr;
        float e = ev[i][j][r];
        uint32_t u = __float_as_uint(e);
        float res = e - __uint_as_float(u & 0xFFFF0000u);
        Phi[lt * PSTR + a] = (short)(u >> 16);
        Plo[lt * PSTR + a] = (short)(__float_as_uint(res) >> 16);
      }
    }
  __syncthreads();

  // ---- PV (3-pass): A = P rows from LDS, B = avT rows (d) ----
  const short* avhp = avThi + (size_t)bh * 4096;
  const short* avlp = avTlo + (size_t)bh * 4096;
  bf16x8 vh_[2][4], vl_[2][4];   // [khalf][j]
#pragma unroll
  for (int j = 0; j < 4; ++j)
#pragma unroll
    for (int kh = 0; kh < 2; ++kh) {
      size_t o = (size_t)(j * 16 + fr) * 64 + kh * 32 + fko;
      vh_[kh][j] = asbf(*(const short8*)(avhp + o));
      vl_[kh][j] = asbf(*(const short8*)(avlp + o));
    }
  bf16x8 ph_[2][2], pl_[2][2];   // [i][khalf]
#pragma unroll
  for (int i = 0; i < 2; ++i)
#pragma unroll
    for (int kh = 0; kh < 2; ++kh) {
      int lt = woff + i * 16 + fr;
      ph_[i][kh] = asbf(*(const short8*)&Phi[lt * PSTR + kh * 32 + fko]);
      pl_[i][kh] = asbf(*(const short8*)&Plo[lt * PSTR + kh * 32 + fko]);
    }
  f32x4 oa[2][4] = {};
#pragma unroll
  for (int i = 0; i < 2; ++i)
#pragma unroll
    for (int j = 0; j < 4; ++j)
#pragma unroll
      for (int kh = 0; kh < 2; ++kh) {
        oa[i][j] = __builtin_amdgcn_mfma_f32_16x16x32_bf16(ph_[i][kh], vh_[kh][j], oa[i][j], 0, 0, 0);
        oa[i][j] = __builtin_amdgcn_mfma_f32_16x16x32_bf16(ph_[i][kh], vl_[kh][j], oa[i][j], 0, 0, 0);
        oa[i][j] = __builtin_amdgcn_mfma_f32_16x16x32_bf16(pl_[i][kh], vh_[kh][j], oa[i][j], 0, 0, 0);
      }

  // ---- normalize + write back into q (out_pre) ----
#pragma unroll
  for (int i = 0; i < 2; ++i)
#pragma unroll
    for (int r = 0; r < 4; ++r) {
      float inv = 1.f / lsum[i][r];
      float* qp = q + (qrow0 + i * 16 + 4 * rg + r) * INNER + h * 64;
#pragma unroll
      for (int j = 0; j < 4; ++j)
        qp[j * 16 + fr] = oa[i][j][r] * inv;
    }
}

// ---------------- depthwise 3x3 conv on v (de-interleaved), added into out_pre ----------------
__global__ __launch_bounds__(256) void dwc4_kernel(const float* __restrict__ v_g,
                                                   const float* __restrict__ dwc_w,
                                                   const float* __restrict__ dwc_b,
                                                   float* __restrict__ outp) {
  int idx = blockIdx.x * 256 + threadIdx.x;    // 16*4096*128 threads
  int cq = (idx & 127) << 2;
  int r  = idx >> 7;
  int x = r & 63, y = (r >> 6) & 63, b = r >> 12;
  float wreg[36];
  {
    const float4* wp = (const float4*)(dwc_w + (size_t)cq * 9);
#pragma unroll
    for (int j = 0; j < 9; ++j) {
      float4 t = wp[j];
      wreg[4 * j + 0] = t.x; wreg[4 * j + 1] = t.y;
      wreg[4 * j + 2] = t.z; wreg[4 * j + 3] = t.w;
    }
  }
  float4 s = *(const float4*)(dwc_b + cq);
  const float* vb = v_g + (size_t)b * NTOK * 512 + cq;
#pragma unroll
  for (int ky = 0; ky < 3; ++ky) {
    int yy = y + ky - 1;
    if (yy < 0 || yy > 63) continue;
#pragma unroll
    for (int kx = 0; kx < 3; ++kx) {
      int xx = x + kx - 1;
      if (xx < 0 || xx > 63) continue;
      float4 v4 = *(const float4*)(vb + (size_t)(yy * 64 + xx) * 512);
      const int t = ky * 3 + kx;
      s.x = fmaf(wreg[0 * 9 + t], v4.x, s.x);
      s.y = fmaf(wreg[1 * 9 + t], v4.y, s.y);
      s.z = fmaf(wreg[2 * 9 + t], v4.z, s.z);
      s.w = fmaf(wreg[3 * 9 + t], v4.w, s.w);
    }
  }
  size_t o = (size_t)r * INNER + cq;
  float4 cur = *(const float4*)(outp + o);
  cur.x += s.x; cur.y += s.y; cur.z += s.z; cur.w += s.w;
  *(float4*)(outp + o) = cur;
}

// ---------------- host launcher ----------------
extern "C" void kernel_launch(void* const* d_in, const int* in_sizes, int n_in,
                              void* d_out, int out_size, void* d_ws, size_t ws_size,
                              hipStream_t stream) {
  const float* x       = (const float*)d_in[0];
  const float* context = (const float*)d_in[1];
  const float* q_w     = (const float*)d_in[2];
  const float* kv_w    = (const float*)d_in[3];
  const float* proj_w  = (const float*)d_in[4];
  const float* proj_b  = (const float*)d_in[5];
  const float* conv_w  = (const float*)d_in[6];
  const float* conv_b  = (const float*)d_in[7];
  const float* dwc_w   = (const float*)d_in[8];
  const float* dwc_b   = (const float*)d_in[9];
  const float* an_bias = (const float*)d_in[10];
  const float* na_bias = (const float*)d_in[11];
  const float* ah_bias = (const float*)d_in[12];
  const float* aw_bias = (const float*)d_in[13];
  const float* ha_bias = (const float*)d_in[14];
  const float* wa_bias = (const float*)d_in[15];
  float* out = (float*)d_out;
  float* wsf = (float*)d_ws;

  float* q_buf  = wsf + Q_OFF;    // later becomes out_pre
  float* k_buf  = wsf + KV_OFF;                              // de-interleaved k: 512-float rows
  float* v_buf  = wsf + KV_OFF + (size_t)BB * NTOK * INNER;  // de-interleaved v
  float* A2     = wsf + A2_OFF;
  float* Col    = wsf + COL_OFF;
  float* Cg     = wsf + CG_OFF;
  float* agent  = wsf + AGT_OFF;
  float* pb     = wsf + PB_OFF;
  float* ab     = wsf + AB_OFF;
  float* pnum   = wsf + PNUM_OFF;  // overlays Col (retired by then)
  float* pl     = wsf + PL_OFF;
  short* avThi  = (short*)(wsf + AVT_OFF);
  short* avTlo  = avThi + (size_t)128 * 64 * 64;
  short* whi    = (short*)(wsf + WSP_OFF);      // rows 0..511 q_w, 512..1535 kv_w, 1536..2047 proj_w
  short* wlo    = whi + (size_t)2048 * 512;
  float* S1q    = wsf + COL_OFF;   // pool scratch (COL region, free until im2col)
  float* S1c    = wsf + CG_OFF;    // pool scratch (CG.. regions, free until conv)

  const int M = BB * NTOK;   // 65536

  // 0. one-time weight splits (fp32 -> bf16 hi/lo)
  split_w_kernel<<<(512 * 512 / 8 + 255) / 256, 256, 0, stream>>>(q_w, whi, wlo, 512 * 512 / 8);
  split_w_kernel<<<(1024 * 512 / 8 + 255) / 256, 256, 0, stream>>>(kv_w, whi + (size_t)512 * 512, wlo + (size_t)512 * 512, 1024 * 512 / 8);
  split_w_kernel<<<(512 * 512 / 8 + 255) / 256, 256, 0, stream>>>(proj_w, whi + (size_t)1536 * 512, wlo + (size_t)1536 * 512, 512 * 512 / 8);

  // 1. fused [q|k|v] = x @ [q_w|kv_w]^T  (MFMA split-bf16, pre-split B, XCD swizzle; 3-way epilogue)
  gemm_ws3<false><<<dim3(1536 / 128, M / 128), 256, 0, stream>>>(x, whi, wlo, nullptr,
                                                                 q_buf, k_buf, v_buf, M, DIMC);
  // 3. separable pooled concat
  pool_h_kernel<<<(BB * 7 * 64 * 768) / 256, 256, 0, stream>>>(q_buf, context, S1q, S1c);
  pool_w_kernel<<<(BB * AG * 768 + 255) / 256, 256, 0, stream>>>(S1q, S1c, A2);
  // 4. im2col
  im2col_kernel<<<(784 * 6912 + 255) / 256, 256, 0, stream>>>(A2, Col);
  // 5. conv as GEMM, split-K with atomics (zero Cg first)
  zero_kernel<<<(784 * INNER + 255) / 256, 256, 0, stream>>>(Cg, 784 * INNER);
  conv_gemm_splitk<<<dim3(INNER / 64, (784 + 63) / 64, CKS), 256, 0, stream>>>(Col, conv_w, Cg);
  // 6. scramble + conv bias -> agent[b,h,a,d]
  agent_scatter_kernel<<<(BB * HEADS * AG * HD + 255) / 256, 256, 0, stream>>>(Cg, conv_b, agent);
  // 7./8. bias tables
  pb_kernel<<<(HEADS * AG * NTOK + 255) / 256, 256, 0, stream>>>(an_bias, ah_bias, aw_bias, pb);
  ab_kernel<<<(HEADS * NTOK * AG + 255) / 256, 256, 0, stream>>>(na_bias, ha_bias, wa_bias, ab);
  // 9. agent attention via MFMA -> partials -> avT (transposed, bf16-split agent_v)
  agent_attn_mfma<<<dim3(ASPLIT, HEADS, BB), 256, 0, stream>>>(k_buf, v_buf, agent, pb, pnum, pl);
  agent_attn_combine<<<(128 * 64 * 64) / 256, 256, 0, stream>>>(pnum, pl, avThi, avTlo);
  // 10. q attention via MFMA (q_buf overwritten with out_pre)
  q_attn_mfma<<<dim3(NTOK / 128, HEADS, BB), 256, 0, stream>>>(agent, avThi, avTlo, ab, q_buf);
  // 11. depthwise conv on v added into out_pre (vectorized: 4 ch/thread, dense v rows)
  dwc4_kernel<<<(BB * NTOK * 128) / 256, 256, 0, stream>>>(v_buf, dwc_w, dwc_b, q_buf);
  // 12. final projection with bias (MFMA, XCD swizzle)
  gemm_ws3<true><<<dim3(DIMC / 128, M / 128), 256, 0, stream>>>(q_buf, whi + (size_t)1536 * 512, wlo + (size_t)1536 * 512,
                                                                proj_b, out, out, out, M, INNER);

  (void)in_sizes; (void)n_in; (void)out_size; (void)ws_size;
}